// Round 5
// baseline (534.847 us; speedup 1.0000x reference)
//
#include <hip/hip_runtime.h>

#define N_PTS   30000
#define M_ATOMS 8000
#define M_PAD   8064
#define D       16
#define KNN     16
#define NGRP    125           // 8000 / 64 exactly
#define EPS     1e-5f
#define SLOPE   0.2f
#define BN_COUNT 480000.0f    // N_PTS * KNN

typedef unsigned long long ull;

__device__ __forceinline__ float leaky(float x) { return x > 0.f ? x : SLOPE * x; }

// sortable key: strictly monotone bijection float -> u32
__device__ __forceinline__ unsigned fkey(float f) {
  unsigned u = __float_as_uint(f);
  return u ^ ((u & 0x80000000u) ? 0xFFFFFFFFu : 0x80000000u);
}

// wave-wide u64 pull-shuffle with precomputed byte address (lane*4)
__device__ __forceinline__ ull bperm64(int addr, ull v) {
  int lo = __builtin_amdgcn_ds_bpermute(addr, (int)(unsigned)(v & 0xFFFFFFFFull));
  int hi = __builtin_amdgcn_ds_bpermute(addr, (int)(unsigned)(v >> 32));
  return ((ull)(unsigned)hi << 32) | (unsigned)lo;
}

// ---------------------------------------------------------------------------
// K1: pack atoms as (x,y,z,|y|^2), transform_types MLP -> t[M,16], zero gstats
// ---------------------------------------------------------------------------
#define LAYER(IN, OUT, W, B)                                        \
  _Pragma("unroll") for (int j = 0; j < 16; ++j) {                  \
    float acc = B[j];                                               \
    _Pragma("unroll") for (int i = 0; i < 16; ++i)                  \
      acc = fmaf(IN[i], W[i*16+j], acc);                            \
    OUT[j] = leaky(acc);                                            \
  }

__global__ void __launch_bounds__(256) k1_prep(
    const float* __restrict__ atom_xyz, const float* __restrict__ atom_types,
    const float* __restrict__ Wt1, const float* __restrict__ bt1,
    const float* __restrict__ Wt2, const float* __restrict__ bt2,
    const float* __restrict__ Wt3, const float* __restrict__ bt3,
    float4* __restrict__ atoms4, float* __restrict__ t_out,
    float* __restrict__ gstats) {
  __shared__ float w1[256], w2[256], w3[256], bb1[16], bb2[16], bb3[16];
  int tid = threadIdx.x;
  if (blockIdx.x == 0 && tid < 64) gstats[tid] = 0.f;
  w1[tid] = Wt1[tid]; w2[tid] = Wt2[tid]; w3[tid] = Wt3[tid];
  if (tid < 16) { bb1[tid] = bt1[tid]; bb2[tid] = bt2[tid]; bb3[tid] = bt3[tid]; }
  __syncthreads();
  int m = blockIdx.x * 256 + tid;
  if (m >= M_ATOMS) return;
  float ax = atom_xyz[m*3+0], ay = atom_xyz[m*3+1], az = atom_xyz[m*3+2];
  atoms4[m] = make_float4(ax, ay, az, fmaf(ax,ax, fmaf(ay,ay, az*az)));

  float u[16], v[16];
  const float4* tp = (const float4*)(atom_types + (size_t)m*16);
  float4 q0 = tp[0], q1 = tp[1], q2 = tp[2], q3 = tp[3];
  u[0]=q0.x; u[1]=q0.y; u[2]=q0.z; u[3]=q0.w;
  u[4]=q1.x; u[5]=q1.y; u[6]=q1.z; u[7]=q1.w;
  u[8]=q2.x; u[9]=q2.y; u[10]=q2.z; u[11]=q2.w;
  u[12]=q3.x; u[13]=q3.y; u[14]=q3.z; u[15]=q3.w;

  LAYER(u, v, w1, bb1);
  LAYER(v, u, w2, bb2);
  LAYER(u, v, w3, bb3);

  float4* op = (float4*)(t_out + (size_t)m*16);
  op[0] = make_float4(v[0], v[1], v[2], v[3]);
  op[1] = make_float4(v[4], v[5], v[6], v[7]);
  op[2] = make_float4(v[8], v[9], v[10], v[11]);
  op[3] = make_float4(v[12], v[13], v[14], v[15]);
}

// ---------------------------------------------------------------------------
// K_SORT: Morton counting sort of atoms on a 16^3 grid (cell 0.5, origin -4).
// Single block, 1024 threads. Output: atoms4s (sorted), origid (perm).
// Order within a cell is atomic-arrival (non-deterministic) — harmless:
// selection uses a strict total order on (d2, origIdx).
// ---------------------------------------------------------------------------
__global__ void __launch_bounds__(1024) k_sort(
    const float4* __restrict__ atoms4, float4* __restrict__ atoms4s,
    int* __restrict__ origid) {
  __shared__ int h0[4096], h1[4096];
  int tid = threadIdx.x;
  for (int i = tid; i < 4096; i += 1024) h0[i] = 0;
  __syncthreads();
  int mycell[8];
#pragma unroll
  for (int r = 0; r < 8; ++r) {
    int m = r*1024 + tid;
    if (m < M_ATOMS) {
      float4 a = atoms4[m];
      int cx = min(max((int)floorf((a.x + 4.f) * 2.f), 0), 15);
      int cy = min(max((int)floorf((a.y + 4.f) * 2.f), 0), 15);
      int cz = min(max((int)floorf((a.z + 4.f) * 2.f), 0), 15);
      int c = 0;
#pragma unroll
      for (int b = 0; b < 4; ++b)
        c |= (((cx>>b)&1) << (3*b)) | (((cy>>b)&1) << (3*b+1)) | (((cz>>b)&1) << (3*b+2));
      mycell[r] = c;
      atomicAdd(&h0[c], 1);
    } else mycell[r] = -1;
  }
  __syncthreads();
  // inclusive scan over 4096 (ping-pong Hillis-Steele, 12 steps)
  int* src = h0; int* dst = h1;
  for (int off = 1; off < 4096; off <<= 1) {
    for (int i = tid; i < 4096; i += 1024) {
      int v = src[i];
      if (i >= off) v += src[i-off];
      dst[i] = v;
    }
    __syncthreads();
    int* tswap = src; src = dst; dst = tswap;
  }
  // exclusive cursor in dst
  for (int i = tid; i < 4096; i += 1024) dst[i] = (i == 0) ? 0 : src[i-1];
  __syncthreads();
#pragma unroll
  for (int r = 0; r < 8; ++r) {
    int m = r*1024 + tid;
    if (m < M_ATOMS) {
      int pos = atomicAdd(&dst[mycell[r]], 1);
      atoms4s[pos] = atoms4[m];
      origid[pos] = m;
    }
  }
}

// ---------------------------------------------------------------------------
// K_BOUNDS: AABB per group of 64 sorted atoms. One wave per group.
// ---------------------------------------------------------------------------
__global__ void __launch_bounds__(256) k_bounds(
    const float4* __restrict__ atoms4s, float4* __restrict__ bounds) {
  int lane = threadIdx.x & 63;
  int g = blockIdx.x * 4 + (threadIdx.x >> 6);
  if (g >= NGRP) return;
  float4 a = atoms4s[(g << 6) + lane];
  float mnx=a.x, mny=a.y, mnz=a.z, mxx=a.x, mxy=a.y, mxz=a.z;
#pragma unroll
  for (int off = 32; off; off >>= 1) {
    mnx = fminf(mnx, __shfl_xor(mnx, off, 64));
    mny = fminf(mny, __shfl_xor(mny, off, 64));
    mnz = fminf(mnz, __shfl_xor(mnz, off, 64));
    mxx = fmaxf(mxx, __shfl_xor(mxx, off, 64));
    mxy = fmaxf(mxy, __shfl_xor(mxy, off, 64));
    mxz = fmaxf(mxz, __shfl_xor(mxz, off, 64));
  }
  if (lane == 0) {
    bounds[2*g]   = make_float4(mnx, mny, mnz, 0.f);
    bounds[2*g+1] = make_float4(mxx, mxy, mxz, 0.f);
  }
}

// ---------------------------------------------------------------------------
// K2 v4: exact 16-NN via best-first group traversal.
// Keys are u64 (fkey(d2)<<32 | origIdx): strict total order == reference
// top_k semantics (ascending d2, ties -> lower original index), independent
// of processing order. Prune: pop groups by ascending AABB lower bound,
// stop when fkey(lb_safe) >= fkey(16th-best d2). lb_safe carries a margin
// covering fp error of the reference's GEMM-expansion metric.
// ---------------------------------------------------------------------------
__global__ void __launch_bounds__(256) k2_knn(
    const float* __restrict__ xyz, const float4* __restrict__ atoms4s,
    const int* __restrict__ origid, const float4* __restrict__ bounds,
    const float* __restrict__ atom_xyz,
    int* __restrict__ knn_idx, float* __restrict__ knn_invd) {
  int lane = threadIdx.x & 63;
  int n = blockIdx.x * 4 + (threadIdx.x >> 6);
  if (n >= N_PTS) return;                    // wave-uniform

  float px = xyz[n*3+0], py = xyz[n*3+1], pz = xyz[n*3+2];
  float x2 = fmaf(px,px, fmaf(py,py, pz*pz));

  // ---- group lower-bound keys (2 groups per lane), depth-2 cursor ----
  ull ea, eb = ~0ull;
  {
    int g = lane;                            // g < 64 <= NGRP-1: always valid
    float4 mn = bounds[2*g], mx = bounds[2*g+1];
    float dx = fmaxf(fmaxf(mn.x - px, px - mx.x), 0.f);
    float dy = fmaxf(fmaxf(mn.y - py, py - mx.y), 0.f);
    float dz = fmaxf(fmaxf(mn.z - pz, pz - mx.z), 0.f);
    float lb = fmaf(dx,dx, fmaf(dy,dy, dz*dz));
    lb = lb * 0.999f - 1e-4f;                // fp-safety margin
    ea = ((ull)fkey(lb) << 32) | (unsigned)g;
  }
  if (lane + 64 < NGRP) {
    int g = lane + 64;
    float4 mn = bounds[2*g], mx = bounds[2*g+1];
    float dx = fmaxf(fmaxf(mn.x - px, px - mx.x), 0.f);
    float dy = fmaxf(fmaxf(mn.y - py, py - mx.y), 0.f);
    float dz = fmaxf(fmaxf(mn.z - pz, pz - mx.z), 0.f);
    float lb = fmaf(dx,dx, fmaf(dy,dy, dz*dz));
    lb = lb * 0.999f - 1e-4f;
    eb = ((ull)fkey(lb) << 32) | (unsigned)g;
  }
  ull cur = ea < eb ? ea : eb;
  ull bak = ea < eb ? eb : ea;

  int ax1  = (lane ^ 1)  << 2, ax2  = (lane ^ 2)  << 2, ax4  = (lane ^ 4) << 2;
  int ax8  = (lane ^ 8)  << 2, ax16 = (lane ^ 16) << 2, ax32 = (lane ^ 32) << 2;

  ull lv = ~0ull;                            // lanes 0..15: sorted top-16 keys
  ull thresh = ~0ull;                        // 16th-best key (wave-uniform)

  for (int iter = 0; iter < NGRP; ++iter) {
    // pop group with min lower-bound key
    ull m = cur;
    { ull o = bperm64(ax1,  m); m = o < m ? o : m; }
    { ull o = bperm64(ax2,  m); m = o < m ? o : m; }
    { ull o = bperm64(ax4,  m); m = o < m ? o : m; }
    { ull o = bperm64(ax8,  m); m = o < m ? o : m; }
    { ull o = bperm64(ax16, m); m = o < m ? o : m; }
    { ull o = bperm64(ax32, m); m = o < m ? o : m; }
    if ((unsigned)(m >> 32) >= (unsigned)(thresh >> 32)) break;  // prune: done
    bool own = (cur == m);
    cur = own ? bak : cur;
    bak = own ? ~0ull : bak;
    int gs = (int)(unsigned)(m & 0xFFFFFFFFull);   // wave-uniform group id

    // process group gs: 64 atoms, coalesced
    int base = gs << 6;
    float4 a = atoms4s[base + lane];
    int oi = origid[base + lane];
    float dotp = fmaf(px,a.x, fmaf(py,a.y, pz*a.z));
    float d2 = (x2 + a.w) - 2.f*dotp;        // reference expansion metric
    ull key = ((ull)fkey(d2) << 32) | (unsigned)oi;

    ull mk = __ballot(key < thresh);
    while (mk) {
      int src = __ffsll(mk) - 1;
      mk &= mk - 1;
      ull kc = __shfl(key, src, 64);
      if (kc < thresh) {
        bool ins = (lane < KNN) && (kc < lv);
        ull pv = __shfl_up(lv, 1, 64);
        int pins = __shfl_up((int)ins, 1, 64);
        if (lane == 0) pins = 0;
        if (ins) lv = pins ? pv : kc;
        thresh = __shfl(lv, KNN-1, 64);
      }
    }
  }

  if (lane < KNN) {
    int oi = (int)(unsigned)(lv & 0xFFFFFFFFull);  // original atom index
    float bx = atom_xyz[oi*3+0], by = atom_xyz[oi*3+1], bz = atom_xyz[oi*3+2];
    float dx = px - bx, dy = py - by, dz = pz - bz;
    float dd = fmaf(dx,dx, fmaf(dy,dy, dz*dz));    // exact recompute (reference)
    knn_idx [n*KNN + lane] = oi;
    knn_invd[n*KNN + lane] = 1.f / dd;
  }
}

// ---------------------------------------------------------------------------
// conv1 (feat[17] @ W1[17,16] + b1) + leaky, weights in LDS
// ---------------------------------------------------------------------------
__device__ __forceinline__ void conv1_leaky(const float* tr, float iv,
                                            const float* w, const float* b,
                                            float* a) {
#pragma unroll
  for (int j = 0; j < 16; ++j) {
    float acc = fmaf(iv, w[256+j], b[j]);
#pragma unroll
    for (int i = 0; i < 16; ++i) acc = fmaf(tr[i], w[i*16+j], acc);
    a[j] = leaky(acc);
  }
}

__device__ __forceinline__ void load_trow(const float* __restrict__ t_in,
                                          int idx, float* tr) {
  const float4* tp = (const float4*)(t_in + (size_t)idx*16);
  float4 q0 = tp[0], q1 = tp[1], q2 = tp[2], q3 = tp[3];
  tr[0]=q0.x; tr[1]=q0.y; tr[2]=q0.z; tr[3]=q0.w;
  tr[4]=q1.x; tr[5]=q1.y; tr[6]=q1.z; tr[7]=q1.w;
  tr[8]=q2.x; tr[9]=q2.y; tr[10]=q2.z; tr[11]=q2.w;
  tr[12]=q3.x; tr[13]=q3.y; tr[14]=q3.z; tr[15]=q3.w;
}

// ---------------------------------------------------------------------------
// K3: BN1 statistics via LDS transpose reduction
// gstats layout: [sum1(16) | sq1(16) | sum2(16) | sq2(16)]
// ---------------------------------------------------------------------------
__global__ void __launch_bounds__(256, 4) k3_stats1(
    const int* __restrict__ knn_idx, const float* __restrict__ knn_invd,
    const float* __restrict__ t_in,
    const float* __restrict__ W1, const float* __restrict__ b1,
    float* __restrict__ gstats) {
  __shared__ float w[272], b[16];
  __shared__ float buf[16*16*17];
  int tid = threadIdx.x;
  w[tid] = W1[tid];
  if (tid < 16) w[256+tid] = W1[256+tid];
  if (tid < 16) b[tid] = b1[tid];
  __syncthreads();

  int g = blockIdx.x * 256 + tid;
  int p = tid >> 4, k = tid & 15;
  int idx = knn_idx[g];
  float iv = knn_invd[g];
  float tr[16], a[16];
  load_trow(t_in, idx, tr);
  conv1_leaky(tr, iv, w, b, a);

  float* myrow = &buf[(p*16 + k)*17];
  int p2 = tid >> 4, j2 = tid & 15;
#pragma unroll
  for (int j = 0; j < 16; ++j) myrow[j] = a[j];
  __syncthreads();
  float s = 0.f;
#pragma unroll
  for (int kk = 0; kk < 16; ++kk) s += buf[(p2*16+kk)*17 + j2];
  __syncthreads();
#pragma unroll
  for (int j = 0; j < 16; ++j) myrow[j] = a[j]*a[j];
  __syncthreads();
  float q = 0.f;
#pragma unroll
  for (int kk = 0; kk < 16; ++kk) q += buf[(p2*16+kk)*17 + j2];
  __syncthreads();
  buf[p2*17 + j2] = s;
  buf[289 + p2*17 + j2] = q;
  __syncthreads();
  if (tid < 16) {
    float t1 = 0.f, t2 = 0.f;
#pragma unroll
    for (int pp = 0; pp < 16; ++pp) { t1 += buf[pp*17 + tid]; t2 += buf[289 + pp*17 + tid]; }
    atomicAdd(&gstats[tid],      t1);
    atomicAdd(&gstats[16 + tid], t2);
  }
}

// ---------------------------------------------------------------------------
// K4: recompute a1, BN1 -> h, fx1 = sum_k h; a2 = leaky(h@W2+b2),
// s2 = sum_k a2; BN2 stats via LDS transpose machinery.
// ---------------------------------------------------------------------------
__global__ void __launch_bounds__(256, 4) k4_main(
    const int* __restrict__ knn_idx, const float* __restrict__ knn_invd,
    const float* __restrict__ t_in,
    const float* __restrict__ W1, const float* __restrict__ b1,
    const float* __restrict__ W2, const float* __restrict__ b2,
    const float* __restrict__ g1, const float* __restrict__ be1,
    float* __restrict__ fx1_out, float* __restrict__ s2_out,
    float* __restrict__ gstats) {
  __shared__ float w1s[272], b1s[16], w2s[256], b2s[16];
  __shared__ float sc1[16], sh1[16];
  __shared__ float buf[16*16*17];
  int tid = threadIdx.x;
  w1s[tid] = W1[tid];
  if (tid < 16) w1s[256+tid] = W1[256+tid];
  w2s[tid] = W2[tid];
  if (tid < 16) { b1s[tid] = b1[tid]; b2s[tid] = b2[tid]; }
  if (tid < 16) {
    float mean = gstats[tid]    * (1.f/BN_COUNT);
    float var  = gstats[16+tid] * (1.f/BN_COUNT) - mean*mean;
    float sC = g1[tid] / sqrtf(var + EPS);
    sc1[tid] = sC;
    sh1[tid] = be1[tid] - mean * sC;
  }
  __syncthreads();

  int g = blockIdx.x * 256 + tid;
  int p = tid >> 4, k = tid & 15;
  int idx = knn_idx[g];
  float iv = knn_invd[g];
  float tr[16], h[16], a2[16];
  load_trow(t_in, idx, tr);
  conv1_leaky(tr, iv, w1s, b1s, h);
#pragma unroll
  for (int j = 0; j < 16; ++j) h[j] = fmaf(h[j], sc1[j], sh1[j]);
#pragma unroll
  for (int j = 0; j < 16; ++j) {
    float accj = b2s[j];
#pragma unroll
    for (int i = 0; i < 16; ++i) accj = fmaf(h[i], w2s[i*16+j], accj);
    a2[j] = leaky(accj);
  }

  float* myrow = &buf[(p*16 + k)*17];
  int p2 = tid >> 4, j2 = tid & 15;
#pragma unroll
  for (int j = 0; j < 16; ++j) myrow[j] = h[j];
  __syncthreads();
  {
    float s = 0.f;
#pragma unroll
    for (int kk = 0; kk < 16; ++kk) s += buf[(p2*16+kk)*17 + j2];
    fx1_out[(size_t)blockIdx.x*256 + tid] = s;
  }
  __syncthreads();
#pragma unroll
  for (int j = 0; j < 16; ++j) myrow[j] = a2[j];
  __syncthreads();
  float s2v = 0.f;
#pragma unroll
  for (int kk = 0; kk < 16; ++kk) s2v += buf[(p2*16+kk)*17 + j2];
  s2_out[(size_t)blockIdx.x*256 + tid] = s2v;
  __syncthreads();
#pragma unroll
  for (int j = 0; j < 16; ++j) myrow[j] = a2[j]*a2[j];
  __syncthreads();
  float q2v = 0.f;
#pragma unroll
  for (int kk = 0; kk < 16; ++kk) q2v += buf[(p2*16+kk)*17 + j2];
  __syncthreads();
  buf[p2*17 + j2] = s2v;
  buf[289 + p2*17 + j2] = q2v;
  __syncthreads();
  if (tid < 16) {
    float t1 = 0.f, t2 = 0.f;
#pragma unroll
    for (int pp = 0; pp < 16; ++pp) { t1 += buf[pp*17 + tid]; t2 += buf[289 + pp*17 + tid]; }
    atomicAdd(&gstats[32 + tid], t1);
    atomicAdd(&gstats[48 + tid], t2);
  }
}

// ---------------------------------------------------------------------------
// K5: fx2 = scale2*s2 + 16*shift2 ; out = [fx1, fx2] @ W3 + b3
// ---------------------------------------------------------------------------
__global__ void __launch_bounds__(256) k5_final(
    const float* __restrict__ fx1_in, const float* __restrict__ s2_in,
    const float* __restrict__ gstats,
    const float* __restrict__ W3, const float* __restrict__ b3,
    const float* __restrict__ g2, const float* __restrict__ be2,
    float* __restrict__ out) {
  __shared__ float w[512], bb[16], sc2[16], sh2[16];
  int tid = threadIdx.x;
  w[tid] = W3[tid]; w[256+tid] = W3[256+tid];
  if (tid < 16) {
    bb[tid] = b3[tid];
    float mean = gstats[32+tid] * (1.f/BN_COUNT);
    float var  = gstats[48+tid] * (1.f/BN_COUNT) - mean*mean;
    float s = g2[tid] / sqrtf(var + EPS);
    sc2[tid] = s;
    sh2[tid] = be2[tid] - mean * s;
  }
  __syncthreads();
  int n = blockIdx.x * 256 + tid;
  if (n >= N_PTS) return;

  float f1[16], f2[16];
  load_trow(fx1_in, n, f1);
  load_trow(s2_in,  n, f2);
#pragma unroll
  for (int i = 0; i < 16; ++i) f2[i] = fmaf(sc2[i], f2[i], 16.f * sh2[i]);

  float4* op = (float4*)(out + (size_t)n*16);
  float o[16];
#pragma unroll
  for (int j = 0; j < 16; ++j) {
    float accj = bb[j];
#pragma unroll
    for (int i = 0; i < 16; ++i) accj = fmaf(f1[i], w[i*16+j], accj);
#pragma unroll
    for (int i = 0; i < 16; ++i) accj = fmaf(f2[i], w[(16+i)*16+j], accj);
    o[j] = accj;
  }
  op[0] = make_float4(o[0], o[1], o[2], o[3]);
  op[1] = make_float4(o[4], o[5], o[6], o[7]);
  op[2] = make_float4(o[8], o[9], o[10], o[11]);
  op[3] = make_float4(o[12], o[13], o[14], o[15]);
}

// ---------------------------------------------------------------------------
extern "C" void kernel_launch(void* const* d_in, const int* in_sizes, int n_in,
                              void* d_out, int out_size, void* d_ws, size_t ws_size,
                              hipStream_t stream) {
  const float* xyz        = (const float*)d_in[0];
  const float* atom_xyz   = (const float*)d_in[1];
  const float* atom_types = (const float*)d_in[2];
  const float* Wt1 = (const float*)d_in[3];  const float* bt1 = (const float*)d_in[4];
  const float* Wt2 = (const float*)d_in[5];  const float* bt2 = (const float*)d_in[6];
  const float* Wt3 = (const float*)d_in[7];  const float* bt3 = (const float*)d_in[8];
  const float* W1  = (const float*)d_in[9];  const float* b1  = (const float*)d_in[10];
  const float* W2  = (const float*)d_in[11]; const float* b2  = (const float*)d_in[12];
  const float* W3  = (const float*)d_in[13]; const float* b3  = (const float*)d_in[14];
  const float* g1  = (const float*)d_in[15]; const float* be1 = (const float*)d_in[16];
  const float* g2  = (const float*)d_in[17]; const float* be2 = (const float*)d_in[18];
  float* out = (float*)d_out;

  float* ws = (float*)d_ws;
  // layout (floats). atoms4s/origid/bounds alias the fx1 region's tail-free
  // space? No: they alias nothing — placed inside fx1's span is NOT allowed
  // since k4 writes fx1. They are placed in fx1's region but used strictly
  // BEFORE k4 runs... k4 writes fx1 only after k2 finished reading. Safe:
  // stream-ordered. (atoms4s+origid+bounds = 41000 floats < 480000.)
  float4* atoms4   = (float4*)ws;                  // 8064*4    = 32256
  float*  t        = ws + 32256;                   // 8000*16   = 128000
  int*    knn_idx  = (int*)(ws + 160256);          // 480000
  float*  knn_invd = ws + 640256;                  // 480000
  float*  fx1      = ws + 1120256;                 // 480000  (k4 output)
  float*  s2       = ws + 1600256;                 // 480000
  float*  gstats   = ws + 2080256;                 // 64
  // kNN accel structures live in fx1's span until k2 completes:
  float4* atoms4s  = (float4*)(ws + 1120256);      // 32000
  int*    origid   = (int*)(ws + 1152256);         // 8000
  float4* bounds   = (float4*)(ws + 1160256);      // 1000

  k1_prep<<<32, 256, 0, stream>>>(atom_xyz, atom_types, Wt1, bt1, Wt2, bt2,
                                  Wt3, bt3, atoms4, t, gstats);
  k_sort<<<1, 1024, 0, stream>>>(atoms4, atoms4s, origid);
  k_bounds<<<32, 256, 0, stream>>>(atoms4s, bounds);
  k2_knn<<<7500, 256, 0, stream>>>(xyz, atoms4s, origid, bounds, atom_xyz,
                                   knn_idx, knn_invd);
  k3_stats1<<<1875, 256, 0, stream>>>(knn_idx, knn_invd, t, W1, b1, gstats);
  k4_main<<<1875, 256, 0, stream>>>(knn_idx, knn_invd, t, W1, b1, W2, b2,
                                    g1, be1, fx1, s2, gstats);
  k5_final<<<118, 256, 0, stream>>>(fx1, s2, gstats, W3, b3, g2, be2, out);
}

// Round 6
// 310.880 us; speedup vs baseline: 1.7204x; 1.7204x over previous
//
#include <hip/hip_runtime.h>

#define N_PTS   30000
#define M_ATOMS 8000
#define D       16
#define KNN     16
#define NGRP    125           // 8000 / 64 exactly
#define EPS     1e-5f
#define SLOPE   0.2f
#define BN_COUNT 480000.0f    // N_PTS * KNN

typedef unsigned long long ull;

__device__ __forceinline__ float leaky(float x) { return x > 0.f ? x : SLOPE * x; }

// sortable key: strictly monotone bijection float -> u32
__device__ __forceinline__ unsigned fkey(float f) {
  unsigned u = __float_as_uint(f);
  return u ^ ((u & 0x80000000u) ? 0xFFFFFFFFu : 0x80000000u);
}

// wave-wide u64 pull-shuffle with precomputed byte address (lane*4)
__device__ __forceinline__ ull bperm64(int addr, ull v) {
  int lo = __builtin_amdgcn_ds_bpermute(addr, (int)(unsigned)(v & 0xFFFFFFFFull));
  int hi = __builtin_amdgcn_ds_bpermute(addr, (int)(unsigned)(v >> 32));
  return ((ull)(unsigned)hi << 32) | (unsigned)lo;
}

__device__ __forceinline__ unsigned wmin32(unsigned v) {
#pragma unroll
  for (int off = 1; off < 64; off <<= 1) {
    unsigned o = (unsigned)__shfl_xor((int)v, off, 64);
    v = o < v ? o : v;
  }
  return v;
}

__device__ __forceinline__ void cswap(ull& a, ull& b) {
  ull mn = a < b ? a : b, mx = a < b ? b : a;
  a = mn; b = mx;
}

// ---------------------------------------------------------------------------
// K1: pack atoms as (x,y,z,|y|^2), transform_types MLP -> t[M,16], zero gstats
// ---------------------------------------------------------------------------
#define LAYER(IN, OUT, W, B)                                        \
  _Pragma("unroll") for (int j = 0; j < 16; ++j) {                  \
    float acc = B[j];                                               \
    _Pragma("unroll") for (int i = 0; i < 16; ++i)                  \
      acc = fmaf(IN[i], W[i*16+j], acc);                            \
    OUT[j] = leaky(acc);                                            \
  }

__global__ void __launch_bounds__(256) k1_prep(
    const float* __restrict__ atom_xyz, const float* __restrict__ atom_types,
    const float* __restrict__ Wt1, const float* __restrict__ bt1,
    const float* __restrict__ Wt2, const float* __restrict__ bt2,
    const float* __restrict__ Wt3, const float* __restrict__ bt3,
    float4* __restrict__ atoms4, float* __restrict__ t_out,
    float* __restrict__ gstats) {
  __shared__ float w1[256], w2[256], w3[256], bb1[16], bb2[16], bb3[16];
  int tid = threadIdx.x;
  if (blockIdx.x == 0 && tid < 64) gstats[tid] = 0.f;
  w1[tid] = Wt1[tid]; w2[tid] = Wt2[tid]; w3[tid] = Wt3[tid];
  if (tid < 16) { bb1[tid] = bt1[tid]; bb2[tid] = bt2[tid]; bb3[tid] = bt3[tid]; }
  __syncthreads();
  int m = blockIdx.x * 256 + tid;
  if (m >= M_ATOMS) return;
  float ax = atom_xyz[m*3+0], ay = atom_xyz[m*3+1], az = atom_xyz[m*3+2];
  atoms4[m] = make_float4(ax, ay, az, fmaf(ax,ax, fmaf(ay,ay, az*az)));

  float u[16], v[16];
  const float4* tp = (const float4*)(atom_types + (size_t)m*16);
  float4 q0 = tp[0], q1 = tp[1], q2 = tp[2], q3 = tp[3];
  u[0]=q0.x; u[1]=q0.y; u[2]=q0.z; u[3]=q0.w;
  u[4]=q1.x; u[5]=q1.y; u[6]=q1.z; u[7]=q1.w;
  u[8]=q2.x; u[9]=q2.y; u[10]=q2.z; u[11]=q2.w;
  u[12]=q3.x; u[13]=q3.y; u[14]=q3.z; u[15]=q3.w;

  LAYER(u, v, w1, bb1);
  LAYER(v, u, w2, bb2);
  LAYER(u, v, w3, bb3);

  float4* op = (float4*)(t_out + (size_t)m*16);
  op[0] = make_float4(v[0], v[1], v[2], v[3]);
  op[1] = make_float4(v[4], v[5], v[6], v[7]);
  op[2] = make_float4(v[8], v[9], v[10], v[11]);
  op[3] = make_float4(v[12], v[13], v[14], v[15]);
}

// ---------------------------------------------------------------------------
// K_SORT: Morton counting sort of atoms on a 16^3 grid (cell 0.5, origin -4).
// ---------------------------------------------------------------------------
__global__ void __launch_bounds__(1024) k_sort(
    const float4* __restrict__ atoms4, float4* __restrict__ atoms4s,
    int* __restrict__ origid) {
  __shared__ int h0[4096], h1[4096];
  int tid = threadIdx.x;
  for (int i = tid; i < 4096; i += 1024) h0[i] = 0;
  __syncthreads();
  int mycell[8];
#pragma unroll
  for (int r = 0; r < 8; ++r) {
    int m = r*1024 + tid;
    if (m < M_ATOMS) {
      float4 a = atoms4[m];
      int cx = min(max((int)floorf((a.x + 4.f) * 2.f), 0), 15);
      int cy = min(max((int)floorf((a.y + 4.f) * 2.f), 0), 15);
      int cz = min(max((int)floorf((a.z + 4.f) * 2.f), 0), 15);
      int c = 0;
#pragma unroll
      for (int b = 0; b < 4; ++b)
        c |= (((cx>>b)&1) << (3*b)) | (((cy>>b)&1) << (3*b+1)) | (((cz>>b)&1) << (3*b+2));
      mycell[r] = c;
      atomicAdd(&h0[c], 1);
    } else mycell[r] = -1;
  }
  __syncthreads();
  int* src = h0; int* dst = h1;
  for (int off = 1; off < 4096; off <<= 1) {
    for (int i = tid; i < 4096; i += 1024) {
      int v = src[i];
      if (i >= off) v += src[i-off];
      dst[i] = v;
    }
    __syncthreads();
    int* tswap = src; src = dst; dst = tswap;
  }
  for (int i = tid; i < 4096; i += 1024) dst[i] = (i == 0) ? 0 : src[i-1];
  __syncthreads();
#pragma unroll
  for (int r = 0; r < 8; ++r) {
    int m = r*1024 + tid;
    if (m < M_ATOMS) {
      int pos = atomicAdd(&dst[mycell[r]], 1);
      atoms4s[pos] = atoms4[m];
      origid[pos] = m;
    }
  }
}

// ---------------------------------------------------------------------------
// K_BOUNDS: AABB per group of 64 sorted atoms. One wave per group.
// ---------------------------------------------------------------------------
__global__ void __launch_bounds__(256) k_bounds(
    const float4* __restrict__ atoms4s, float4* __restrict__ bounds) {
  int lane = threadIdx.x & 63;
  int g = blockIdx.x * 4 + (threadIdx.x >> 6);
  if (g >= NGRP) return;
  float4 a = atoms4s[(g << 6) + lane];
  float mnx=a.x, mny=a.y, mnz=a.z, mxx=a.x, mxy=a.y, mxz=a.z;
#pragma unroll
  for (int off = 32; off; off >>= 1) {
    mnx = fminf(mnx, __shfl_xor(mnx, off, 64));
    mny = fminf(mny, __shfl_xor(mny, off, 64));
    mnz = fminf(mnz, __shfl_xor(mnz, off, 64));
    mxx = fmaxf(mxx, __shfl_xor(mxx, off, 64));
    mxy = fmaxf(mxy, __shfl_xor(mxy, off, 64));
    mxz = fmaxf(mxz, __shfl_xor(mxz, off, 64));
  }
  if (lane == 0) {
    bounds[2*g]   = make_float4(mnx, mny, mnz, 0.f);
    bounds[2*g+1] = make_float4(mxx, mxy, mxz, 0.f);
  }
}

// ---------------------------------------------------------------------------
// K2 v5: exact 16-NN. Pop 4 nearest groups (u32 lb keys, shfl butterflies),
// process their 256 atoms branchlessly = 4 keys/lane (lossless), one 16-round
// bperm64 cursor-merge -> top-16 + thresh, then residual groups (rarely any
// candidates) with ballot-guarded serial insert. Keys (fkey(d2)<<32|origIdx)
// form a strict total order == reference top_k tie semantics, order-independent.
// ---------------------------------------------------------------------------
__global__ void __launch_bounds__(256) k2_knn(
    const float* __restrict__ xyz, const float4* __restrict__ atoms4s,
    const int* __restrict__ origid, const float4* __restrict__ bounds,
    const float* __restrict__ atom_xyz,
    int* __restrict__ knn_idx, float* __restrict__ knn_invd) {
  int lane = threadIdx.x & 63;
  int n = blockIdx.x * 4 + (threadIdx.x >> 6);
  if (n >= N_PTS) return;                    // wave-uniform

  float px = xyz[n*3+0], py = xyz[n*3+1], pz = xyz[n*3+2];
  float x2 = fmaf(px,px, fmaf(py,py, pz*pz));

  // ---- group lower-bound keys, packed u32: trunc24(fkey(lb)) | group ----
  unsigned ea, eb = 0xFFFFFFFFu;
  {
    int g = lane;                            // lane < 64 < NGRP: always valid
    float4 mn = bounds[2*g], mx = bounds[2*g+1];
    float dx = fmaxf(fmaxf(mn.x - px, px - mx.x), 0.f);
    float dy = fmaxf(fmaxf(mn.y - py, py - mx.y), 0.f);
    float dz = fmaxf(fmaxf(mn.z - pz, pz - mx.z), 0.f);
    float lb = fmaf(dx,dx, fmaf(dy,dy, dz*dz)) * 0.999f - 1e-4f;
    ea = (fkey(lb) & 0xFFFFFF00u) | (unsigned)g;
  }
  if (lane + 64 < NGRP) {
    int g = lane + 64;
    float4 mn = bounds[2*g], mx = bounds[2*g+1];
    float dx = fmaxf(fmaxf(mn.x - px, px - mx.x), 0.f);
    float dy = fmaxf(fmaxf(mn.y - py, py - mx.y), 0.f);
    float dz = fmaxf(fmaxf(mn.z - pz, pz - mx.z), 0.f);
    float lb = fmaf(dx,dx, fmaf(dy,dy, dz*dz)) * 0.999f - 1e-4f;
    eb = (fkey(lb) & 0xFFFFFF00u) | (unsigned)g;
  }
  unsigned cur = ea < eb ? ea : eb;
  unsigned bak = ea < eb ? eb : ea;

  // ---- pop the 4 nearest groups ----
  int gs[4];
#pragma unroll
  for (int r = 0; r < 4; ++r) {
    unsigned m = wmin32(cur);
    bool own = (cur == m);
    cur = own ? bak : cur;
    bak = own ? 0xFFFFFFFFu : bak;
    gs[r] = (int)(m & 0xFFu);
  }

  // ---- branchless: 4 atoms/lane -> exact u64 keys, sort-4 network ----
  float4 A[4]; int OI[4];
#pragma unroll
  for (int r = 0; r < 4; ++r) {
    int base = gs[r] << 6;
    A[r]  = atoms4s[base + lane];
    OI[r] = origid [base + lane];
  }
  ull E[4];
#pragma unroll
  for (int r = 0; r < 4; ++r) {
    float dotp = fmaf(px,A[r].x, fmaf(py,A[r].y, pz*A[r].z));
    float d2 = (x2 + A[r].w) - 2.f*dotp;     // reference expansion metric
    E[r] = ((ull)fkey(d2) << 32) | (unsigned)OI[r];
  }
  cswap(E[0],E[1]); cswap(E[2],E[3]); cswap(E[0],E[2]);
  cswap(E[1],E[3]); cswap(E[1],E[2]);

  // ---- 16-round cursor merge over 64x4 candidates (exact) ----
  int ax1  = (lane ^ 1)  << 2, ax2  = (lane ^ 2)  << 2, ax4  = (lane ^ 4) << 2;
  int ax8  = (lane ^ 8)  << 2, ax16 = (lane ^ 16) << 2, ax32 = (lane ^ 32) << 2;
  ull c64 = E[0], l1 = E[1], l2 = E[2], l3 = E[3];
  ull res = ~0ull, m64 = 0;
  for (int r = 0; r < KNN; ++r) {
    m64 = c64;
    { ull o = bperm64(ax1,  m64); m64 = o < m64 ? o : m64; }
    { ull o = bperm64(ax2,  m64); m64 = o < m64 ? o : m64; }
    { ull o = bperm64(ax4,  m64); m64 = o < m64 ? o : m64; }
    { ull o = bperm64(ax8,  m64); m64 = o < m64 ? o : m64; }
    { ull o = bperm64(ax16, m64); m64 = o < m64 ? o : m64; }
    { ull o = bperm64(ax32, m64); m64 = o < m64 ? o : m64; }
    if (lane == r) res = m64;
    bool own = (c64 == m64);
    c64 = own ? l1 : c64;
    l1  = own ? l2 : l1;
    l2  = own ? l3 : l2;
    l3  = own ? ~0ull : l3;
  }
  ull lv = res;                              // lane r (<16): r-th best key
  ull thresh = m64;                          // 16th best (wave-uniform)

  // ---- residual groups: pop while lb < thresh (usually 0 inserts) ----
  for (int it = 0; it < NGRP - 4; ++it) {
    unsigned m = wmin32(cur);
    if ((m & 0xFFFFFF00u) >= (unsigned)(thresh >> 32)) break;   // prune done
    bool own = (cur == m);
    cur = own ? bak : cur;
    bak = own ? 0xFFFFFFFFu : bak;
    int base = (int)(m & 0xFFu) << 6;

    float4 a = atoms4s[base + lane];
    int oi = origid[base + lane];
    float dotp = fmaf(px,a.x, fmaf(py,a.y, pz*a.z));
    float d2 = (x2 + a.w) - 2.f*dotp;
    ull key = ((ull)fkey(d2) << 32) | (unsigned)oi;

    ull mk = __ballot(key < thresh);
    while (mk) {
      int src = __ffsll(mk) - 1;
      mk &= mk - 1;
      ull kc = __shfl(key, src, 64);
      if (kc < thresh) {
        bool ins = (lane < KNN) && (kc < lv);
        ull pv = __shfl_up(lv, 1, 64);
        int pins = __shfl_up((int)ins, 1, 64);
        if (lane == 0) pins = 0;
        if (ins) lv = pins ? pv : kc;
        thresh = __shfl(lv, KNN-1, 64);
      }
    }
  }

  if (lane < KNN) {
    int oi = (int)(unsigned)(lv & 0xFFFFFFFFull);
    float bx = atom_xyz[oi*3+0], by = atom_xyz[oi*3+1], bz = atom_xyz[oi*3+2];
    float dx = px - bx, dy = py - by, dz = pz - bz;
    float dd = fmaf(dx,dx, fmaf(dy,dy, dz*dz));    // exact recompute (reference)
    knn_idx [n*KNN + lane] = oi;
    knn_invd[n*KNN + lane] = 1.f / dd;
  }
}

// ---------------------------------------------------------------------------
// conv1 (feat[17] @ W1[17,16] + b1) + leaky, weights in LDS
// ---------------------------------------------------------------------------
__device__ __forceinline__ void conv1_leaky(const float* tr, float iv,
                                            const float* w, const float* b,
                                            float* a) {
#pragma unroll
  for (int j = 0; j < 16; ++j) {
    float acc = fmaf(iv, w[256+j], b[j]);
#pragma unroll
    for (int i = 0; i < 16; ++i) acc = fmaf(tr[i], w[i*16+j], acc);
    a[j] = leaky(acc);
  }
}

__device__ __forceinline__ void load_trow(const float* __restrict__ t_in,
                                          int idx, float* tr) {
  const float4* tp = (const float4*)(t_in + (size_t)idx*16);
  float4 q0 = tp[0], q1 = tp[1], q2 = tp[2], q3 = tp[3];
  tr[0]=q0.x; tr[1]=q0.y; tr[2]=q0.z; tr[3]=q0.w;
  tr[4]=q1.x; tr[5]=q1.y; tr[6]=q1.z; tr[7]=q1.w;
  tr[8]=q2.x; tr[9]=q2.y; tr[10]=q2.z; tr[11]=q2.w;
  tr[12]=q3.x; tr[13]=q3.y; tr[14]=q3.z; tr[15]=q3.w;
}

// ---------------------------------------------------------------------------
// K3: BN1 statistics via LDS transpose reduction
// gstats layout: [sum1(16) | sq1(16) | sum2(16) | sq2(16)]
// ---------------------------------------------------------------------------
__global__ void __launch_bounds__(256, 4) k3_stats1(
    const int* __restrict__ knn_idx, const float* __restrict__ knn_invd,
    const float* __restrict__ t_in,
    const float* __restrict__ W1, const float* __restrict__ b1,
    float* __restrict__ gstats) {
  __shared__ float w[272], b[16];
  __shared__ float buf[16*16*17];
  int tid = threadIdx.x;
  w[tid] = W1[tid];
  if (tid < 16) w[256+tid] = W1[256+tid];
  if (tid < 16) b[tid] = b1[tid];
  __syncthreads();

  int g = blockIdx.x * 256 + tid;
  int p = tid >> 4, k = tid & 15;
  int idx = knn_idx[g];
  float iv = knn_invd[g];
  float tr[16], a[16];
  load_trow(t_in, idx, tr);
  conv1_leaky(tr, iv, w, b, a);

  float* myrow = &buf[(p*16 + k)*17];
  int p2 = tid >> 4, j2 = tid & 15;
#pragma unroll
  for (int j = 0; j < 16; ++j) myrow[j] = a[j];
  __syncthreads();
  float s = 0.f;
#pragma unroll
  for (int kk = 0; kk < 16; ++kk) s += buf[(p2*16+kk)*17 + j2];
  __syncthreads();
#pragma unroll
  for (int j = 0; j < 16; ++j) myrow[j] = a[j]*a[j];
  __syncthreads();
  float q = 0.f;
#pragma unroll
  for (int kk = 0; kk < 16; ++kk) q += buf[(p2*16+kk)*17 + j2];
  __syncthreads();
  buf[p2*17 + j2] = s;
  buf[289 + p2*17 + j2] = q;
  __syncthreads();
  if (tid < 16) {
    float t1 = 0.f, t2 = 0.f;
#pragma unroll
    for (int pp = 0; pp < 16; ++pp) { t1 += buf[pp*17 + tid]; t2 += buf[289 + pp*17 + tid]; }
    atomicAdd(&gstats[tid],      t1);
    atomicAdd(&gstats[16 + tid], t2);
  }
}

// ---------------------------------------------------------------------------
// K4: recompute a1, BN1 -> h, fx1 = sum_k h; a2 = leaky(h@W2+b2),
// s2 = sum_k a2; BN2 stats via LDS transpose machinery.
// ---------------------------------------------------------------------------
__global__ void __launch_bounds__(256, 4) k4_main(
    const int* __restrict__ knn_idx, const float* __restrict__ knn_invd,
    const float* __restrict__ t_in,
    const float* __restrict__ W1, const float* __restrict__ b1,
    const float* __restrict__ W2, const float* __restrict__ b2,
    const float* __restrict__ g1, const float* __restrict__ be1,
    float* __restrict__ fx1_out, float* __restrict__ s2_out,
    float* __restrict__ gstats) {
  __shared__ float w1s[272], b1s[16], w2s[256], b2s[16];
  __shared__ float sc1[16], sh1[16];
  __shared__ float buf[16*16*17];
  int tid = threadIdx.x;
  w1s[tid] = W1[tid];
  if (tid < 16) w1s[256+tid] = W1[256+tid];
  w2s[tid] = W2[tid];
  if (tid < 16) { b1s[tid] = b1[tid]; b2s[tid] = b2[tid]; }
  if (tid < 16) {
    float mean = gstats[tid]    * (1.f/BN_COUNT);
    float var  = gstats[16+tid] * (1.f/BN_COUNT) - mean*mean;
    float sC = g1[tid] / sqrtf(var + EPS);
    sc1[tid] = sC;
    sh1[tid] = be1[tid] - mean * sC;
  }
  __syncthreads();

  int g = blockIdx.x * 256 + tid;
  int p = tid >> 4, k = tid & 15;
  int idx = knn_idx[g];
  float iv = knn_invd[g];
  float tr[16], h[16], a2[16];
  load_trow(t_in, idx, tr);
  conv1_leaky(tr, iv, w1s, b1s, h);
#pragma unroll
  for (int j = 0; j < 16; ++j) h[j] = fmaf(h[j], sc1[j], sh1[j]);
#pragma unroll
  for (int j = 0; j < 16; ++j) {
    float accj = b2s[j];
#pragma unroll
    for (int i = 0; i < 16; ++i) accj = fmaf(h[i], w2s[i*16+j], accj);
    a2[j] = leaky(accj);
  }

  float* myrow = &buf[(p*16 + k)*17];
  int p2 = tid >> 4, j2 = tid & 15;
#pragma unroll
  for (int j = 0; j < 16; ++j) myrow[j] = h[j];
  __syncthreads();
  {
    float s = 0.f;
#pragma unroll
    for (int kk = 0; kk < 16; ++kk) s += buf[(p2*16+kk)*17 + j2];
    fx1_out[(size_t)blockIdx.x*256 + tid] = s;
  }
  __syncthreads();
#pragma unroll
  for (int j = 0; j < 16; ++j) myrow[j] = a2[j];
  __syncthreads();
  float s2v = 0.f;
#pragma unroll
  for (int kk = 0; kk < 16; ++kk) s2v += buf[(p2*16+kk)*17 + j2];
  s2_out[(size_t)blockIdx.x*256 + tid] = s2v;
  __syncthreads();
#pragma unroll
  for (int j = 0; j < 16; ++j) myrow[j] = a2[j]*a2[j];
  __syncthreads();
  float q2v = 0.f;
#pragma unroll
  for (int kk = 0; kk < 16; ++kk) q2v += buf[(p2*16+kk)*17 + j2];
  __syncthreads();
  buf[p2*17 + j2] = s2v;
  buf[289 + p2*17 + j2] = q2v;
  __syncthreads();
  if (tid < 16) {
    float t1 = 0.f, t2 = 0.f;
#pragma unroll
    for (int pp = 0; pp < 16; ++pp) { t1 += buf[pp*17 + tid]; t2 += buf[289 + pp*17 + tid]; }
    atomicAdd(&gstats[32 + tid], t1);
    atomicAdd(&gstats[48 + tid], t2);
  }
}

// ---------------------------------------------------------------------------
// K5: fx2 = scale2*s2 + 16*shift2 ; out = [fx1, fx2] @ W3 + b3
// ---------------------------------------------------------------------------
__global__ void __launch_bounds__(256) k5_final(
    const float* __restrict__ fx1_in, const float* __restrict__ s2_in,
    const float* __restrict__ gstats,
    const float* __restrict__ W3, const float* __restrict__ b3,
    const float* __restrict__ g2, const float* __restrict__ be2,
    float* __restrict__ out) {
  __shared__ float w[512], bb[16], sc2[16], sh2[16];
  int tid = threadIdx.x;
  w[tid] = W3[tid]; w[256+tid] = W3[256+tid];
  if (tid < 16) {
    bb[tid] = b3[tid];
    float mean = gstats[32+tid] * (1.f/BN_COUNT);
    float var  = gstats[48+tid] * (1.f/BN_COUNT) - mean*mean;
    float s = g2[tid] / sqrtf(var + EPS);
    sc2[tid] = s;
    sh2[tid] = be2[tid] - mean * s;
  }
  __syncthreads();
  int n = blockIdx.x * 256 + tid;
  if (n >= N_PTS) return;

  float f1[16], f2[16];
  load_trow(fx1_in, n, f1);
  load_trow(s2_in,  n, f2);
#pragma unroll
  for (int i = 0; i < 16; ++i) f2[i] = fmaf(sc2[i], f2[i], 16.f * sh2[i]);

  float4* op = (float4*)(out + (size_t)n*16);
  float o[16];
#pragma unroll
  for (int j = 0; j < 16; ++j) {
    float accj = bb[j];
#pragma unroll
    for (int i = 0; i < 16; ++i) accj = fmaf(f1[i], w[i*16+j], accj);
#pragma unroll
    for (int i = 0; i < 16; ++i) accj = fmaf(f2[i], w[(16+i)*16+j], accj);
    o[j] = accj;
  }
  op[0] = make_float4(o[0], o[1], o[2], o[3]);
  op[1] = make_float4(o[4], o[5], o[6], o[7]);
  op[2] = make_float4(o[8], o[9], o[10], o[11]);
  op[3] = make_float4(o[12], o[13], o[14], o[15]);
}

// ---------------------------------------------------------------------------
extern "C" void kernel_launch(void* const* d_in, const int* in_sizes, int n_in,
                              void* d_out, int out_size, void* d_ws, size_t ws_size,
                              hipStream_t stream) {
  const float* xyz        = (const float*)d_in[0];
  const float* atom_xyz   = (const float*)d_in[1];
  const float* atom_types = (const float*)d_in[2];
  const float* Wt1 = (const float*)d_in[3];  const float* bt1 = (const float*)d_in[4];
  const float* Wt2 = (const float*)d_in[5];  const float* bt2 = (const float*)d_in[6];
  const float* Wt3 = (const float*)d_in[7];  const float* bt3 = (const float*)d_in[8];
  const float* W1  = (const float*)d_in[9];  const float* b1  = (const float*)d_in[10];
  const float* W2  = (const float*)d_in[11]; const float* b2  = (const float*)d_in[12];
  const float* W3  = (const float*)d_in[13]; const float* b3  = (const float*)d_in[14];
  const float* g1  = (const float*)d_in[15]; const float* be1 = (const float*)d_in[16];
  const float* g2  = (const float*)d_in[17]; const float* be2 = (const float*)d_in[18];
  float* out = (float*)d_out;

  float* ws = (float*)d_ws;
  float4* atoms4   = (float4*)ws;                  // 8064*4    = 32256
  float*  t        = ws + 32256;                   // 8000*16   = 128000
  int*    knn_idx  = (int*)(ws + 160256);          // 480000
  float*  knn_invd = ws + 640256;                  // 480000
  float*  fx1      = ws + 1120256;                 // 480000  (k4 output)
  float*  s2       = ws + 1600256;                 // 480000
  float*  gstats   = ws + 2080256;                 // 64
  // kNN accel structures live in fx1's span until k2 completes (stream-ordered):
  float4* atoms4s  = (float4*)(ws + 1120256);      // 32000
  int*    origid   = (int*)(ws + 1152256);         // 8000
  float4* bounds   = (float4*)(ws + 1160256);      // 1000

  k1_prep<<<32, 256, 0, stream>>>(atom_xyz, atom_types, Wt1, bt1, Wt2, bt2,
                                  Wt3, bt3, atoms4, t, gstats);
  k_sort<<<1, 1024, 0, stream>>>(atoms4, atoms4s, origid);
  k_bounds<<<32, 256, 0, stream>>>(atoms4s, bounds);
  k2_knn<<<7500, 256, 0, stream>>>(xyz, atoms4s, origid, bounds, atom_xyz,
                                   knn_idx, knn_invd);
  k3_stats1<<<1875, 256, 0, stream>>>(knn_idx, knn_invd, t, W1, b1, gstats);
  k4_main<<<1875, 256, 0, stream>>>(knn_idx, knn_invd, t, W1, b1, W2, b2,
                                    g1, be1, fx1, s2, gstats);
  k5_final<<<118, 256, 0, stream>>>(fx1, s2, gstats, W3, b3, g2, be2, out);
}

// Round 8
// 262.676 us; speedup vs baseline: 2.0361x; 1.1835x over previous
//
#include <hip/hip_runtime.h>

#define N_PTS   30000
#define M_ATOMS 8000
#define D       16
#define KNN     16
#define NGRP    125           // 8000 / 64 exactly
#define EPS     1e-5f
#define SLOPE   0.2f
#define BN_COUNT 480000.0f    // N_PTS * KNN

typedef unsigned long long ull;

__device__ __forceinline__ float leaky(float x) { return x > 0.f ? x : SLOPE * x; }

// sortable key: strictly monotone bijection float -> u32
__device__ __forceinline__ unsigned fkey(float f) {
  unsigned u = __float_as_uint(f);
  return u ^ ((u & 0x80000000u) ? 0xFFFFFFFFu : 0x80000000u);
}

// ---- DPP wave-min reductions (VALU latency, no LDS round-trips) ----
// row_shr:n = 0x110|n (lane i <- lane i-n, toward HIGHER lanes, = shfl_up)
// row_shl:n = 0x100|n (lane i <- lane i+n) -- NOT shfl_up! (R7 bug)
// row_bcast15 = 0x142, row_bcast31 = 0x143; reduce lands in lane 63.
#define DPPSTEP32(v, CTRL) {                                                   \
  unsigned t_ = (unsigned)__builtin_amdgcn_update_dpp(-1, (int)(v), CTRL, 0xF, 0xF, false); \
  (v) = t_ < (v) ? t_ : (v); }

__device__ __forceinline__ unsigned wmin32d(unsigned v) {
  DPPSTEP32(v, 0x111); DPPSTEP32(v, 0x112); DPPSTEP32(v, 0x114);
  DPPSTEP32(v, 0x118); DPPSTEP32(v, 0x142); DPPSTEP32(v, 0x143);
  return (unsigned)__builtin_amdgcn_readlane((int)v, 63);   // wave-uniform
}

#define DPPSTEP64(lo, hi, CTRL) {                                              \
  unsigned tlo_ = (unsigned)__builtin_amdgcn_update_dpp(-1, (int)(lo), CTRL, 0xF, 0xF, false); \
  unsigned thi_ = (unsigned)__builtin_amdgcn_update_dpp(-1, (int)(hi), CTRL, 0xF, 0xF, false); \
  bool lt_ = (thi_ < (hi)) || ((thi_ == (hi)) && (tlo_ < (lo)));               \
  (lo) = lt_ ? tlo_ : (lo); (hi) = lt_ ? thi_ : (hi); }

__device__ __forceinline__ ull wmin64d(ull v) {
  unsigned lo = (unsigned)v, hi = (unsigned)(v >> 32);
  DPPSTEP64(lo, hi, 0x111); DPPSTEP64(lo, hi, 0x112); DPPSTEP64(lo, hi, 0x114);
  DPPSTEP64(lo, hi, 0x118); DPPSTEP64(lo, hi, 0x142); DPPSTEP64(lo, hi, 0x143);
  unsigned flo = (unsigned)__builtin_amdgcn_readlane((int)lo, 63);
  unsigned fhi = (unsigned)__builtin_amdgcn_readlane((int)hi, 63);
  return ((ull)fhi << 32) | flo;
}

__device__ __forceinline__ void cswap(ull& a, ull& b) {
  ull mn = a < b ? a : b, mx = a < b ? b : a;
  a = mn; b = mx;
}

// ---------------------------------------------------------------------------
// K1: atoms4 (x,y,z,|y|^2); t = 3-layer MLP; u' = t@W1 + b1 (conv1 folded);
// zero gstats.
// ---------------------------------------------------------------------------
#define LAYER(IN, OUT, W, B)                                        \
  _Pragma("unroll") for (int j = 0; j < 16; ++j) {                  \
    float acc = B[j];                                               \
    _Pragma("unroll") for (int i = 0; i < 16; ++i)                  \
      acc = fmaf(IN[i], W[i*16+j], acc);                            \
    OUT[j] = leaky(acc);                                            \
  }

__global__ void __launch_bounds__(256) k1_prep(
    const float* __restrict__ atom_xyz, const float* __restrict__ atom_types,
    const float* __restrict__ Wt1, const float* __restrict__ bt1,
    const float* __restrict__ Wt2, const float* __restrict__ bt2,
    const float* __restrict__ Wt3, const float* __restrict__ bt3,
    const float* __restrict__ W1, const float* __restrict__ b1,
    float4* __restrict__ atoms4, float* __restrict__ tu_out,
    float* __restrict__ gstats) {
  __shared__ float w1[256], w2[256], w3[256], wc[256];
  __shared__ float bb1[16], bb2[16], bb3[16], bbc[16];
  int tid = threadIdx.x;
  if (blockIdx.x == 0 && tid < 64) gstats[tid] = 0.f;
  w1[tid] = Wt1[tid]; w2[tid] = Wt2[tid]; w3[tid] = Wt3[tid]; wc[tid] = W1[tid];
  if (tid < 16) { bb1[tid] = bt1[tid]; bb2[tid] = bt2[tid]; bb3[tid] = bt3[tid]; bbc[tid] = b1[tid]; }
  __syncthreads();
  int m = blockIdx.x * 256 + tid;
  if (m >= M_ATOMS) return;
  float ax = atom_xyz[m*3+0], ay = atom_xyz[m*3+1], az = atom_xyz[m*3+2];
  atoms4[m] = make_float4(ax, ay, az, fmaf(ax,ax, fmaf(ay,ay, az*az)));

  float u[16], v[16];
  const float4* tp = (const float4*)(atom_types + (size_t)m*16);
  float4 q0 = tp[0], q1 = tp[1], q2 = tp[2], q3 = tp[3];
  u[0]=q0.x; u[1]=q0.y; u[2]=q0.z; u[3]=q0.w;
  u[4]=q1.x; u[5]=q1.y; u[6]=q1.z; u[7]=q1.w;
  u[8]=q2.x; u[9]=q2.y; u[10]=q2.z; u[11]=q2.w;
  u[12]=q3.x; u[13]=q3.y; u[14]=q3.z; u[15]=q3.w;

  LAYER(u, v, w1, bb1);
  LAYER(v, u, w2, bb2);
  LAYER(u, v, w3, bb3);
  // u' = t @ W1[0:16,:] + b1  (no leaky; conv1's linear t-part)
  float up[16];
#pragma unroll
  for (int j = 0; j < 16; ++j) {
    float acc = bbc[j];
#pragma unroll
    for (int i = 0; i < 16; ++i) acc = fmaf(v[i], wc[i*16+j], acc);
    up[j] = acc;
  }

  float4* op = (float4*)(tu_out + (size_t)m*16);
  op[0] = make_float4(up[0], up[1], up[2], up[3]);
  op[1] = make_float4(up[4], up[5], up[6], up[7]);
  op[2] = make_float4(up[8], up[9], up[10], up[11]);
  op[3] = make_float4(up[12], up[13], up[14], up[15]);
}

// ---------------------------------------------------------------------------
// K_SORT: Morton counting sort of atoms on a 16^3 grid (cell 0.5, origin -4).
// ---------------------------------------------------------------------------
__global__ void __launch_bounds__(1024) k_sort(
    const float4* __restrict__ atoms4, float4* __restrict__ atoms4s,
    int* __restrict__ origid) {
  __shared__ int h0[4096], h1[4096];
  int tid = threadIdx.x;
  for (int i = tid; i < 4096; i += 1024) h0[i] = 0;
  __syncthreads();
  int mycell[8];
#pragma unroll
  for (int r = 0; r < 8; ++r) {
    int m = r*1024 + tid;
    if (m < M_ATOMS) {
      float4 a = atoms4[m];
      int cx = min(max((int)floorf((a.x + 4.f) * 2.f), 0), 15);
      int cy = min(max((int)floorf((a.y + 4.f) * 2.f), 0), 15);
      int cz = min(max((int)floorf((a.z + 4.f) * 2.f), 0), 15);
      int c = 0;
#pragma unroll
      for (int b = 0; b < 4; ++b)
        c |= (((cx>>b)&1) << (3*b)) | (((cy>>b)&1) << (3*b+1)) | (((cz>>b)&1) << (3*b+2));
      mycell[r] = c;
      atomicAdd(&h0[c], 1);
    } else mycell[r] = -1;
  }
  __syncthreads();
  int* src = h0; int* dst = h1;
  for (int off = 1; off < 4096; off <<= 1) {
    for (int i = tid; i < 4096; i += 1024) {
      int v = src[i];
      if (i >= off) v += src[i-off];
      dst[i] = v;
    }
    __syncthreads();
    int* tswap = src; src = dst; dst = tswap;
  }
  for (int i = tid; i < 4096; i += 1024) dst[i] = (i == 0) ? 0 : src[i-1];
  __syncthreads();
#pragma unroll
  for (int r = 0; r < 8; ++r) {
    int m = r*1024 + tid;
    if (m < M_ATOMS) {
      int pos = atomicAdd(&dst[mycell[r]], 1);
      atoms4s[pos] = atoms4[m];
      origid[pos] = m;
    }
  }
}

// ---------------------------------------------------------------------------
// K_BOUNDS: AABB per group of 64 sorted atoms. One wave per group.
// ---------------------------------------------------------------------------
__global__ void __launch_bounds__(256) k_bounds(
    const float4* __restrict__ atoms4s, float4* __restrict__ bounds) {
  int lane = threadIdx.x & 63;
  int g = blockIdx.x * 4 + (threadIdx.x >> 6);
  if (g >= NGRP) return;
  float4 a = atoms4s[(g << 6) + lane];
  float mnx=a.x, mny=a.y, mnz=a.z, mxx=a.x, mxy=a.y, mxz=a.z;
#pragma unroll
  for (int off = 32; off; off >>= 1) {
    mnx = fminf(mnx, __shfl_xor(mnx, off, 64));
    mny = fminf(mny, __shfl_xor(mny, off, 64));
    mnz = fminf(mnz, __shfl_xor(mnz, off, 64));
    mxx = fmaxf(mxx, __shfl_xor(mxx, off, 64));
    mxy = fmaxf(mxy, __shfl_xor(mxy, off, 64));
    mxz = fmaxf(mxz, __shfl_xor(mxz, off, 64));
  }
  if (lane == 0) {
    bounds[2*g]   = make_float4(mnx, mny, mnz, 0.f);
    bounds[2*g+1] = make_float4(mxx, mxy, mxz, 0.f);
  }
}

// ---------------------------------------------------------------------------
// K2 v6b: exact 16-NN; cross-lane via DPP + readlane. Pop 4 nearest groups
// -> 4 exact u64 keys/lane (lossless) -> 16-round DPP cursor merge -> thresh;
// residual groups: DPP pop + readlane serial insert (row_shr:1 = shfl_up).
// Key (fkey(d2)<<32 | origIdx) = strict total order == reference top_k.
// ---------------------------------------------------------------------------
__global__ void __launch_bounds__(256) k2_knn(
    const float* __restrict__ xyz, const float4* __restrict__ atoms4s,
    const int* __restrict__ origid, const float4* __restrict__ bounds,
    const float* __restrict__ atom_xyz,
    int2* __restrict__ pairs) {
  int lane = threadIdx.x & 63;
  int n = blockIdx.x * 4 + (threadIdx.x >> 6);
  if (n >= N_PTS) return;                    // wave-uniform (30000 = 7500*4)

  float px = xyz[n*3+0], py = xyz[n*3+1], pz = xyz[n*3+2];
  float x2 = fmaf(px,px, fmaf(py,py, pz*pz));

  // ---- group lower-bound keys, packed u32: trunc24(fkey(lb)) | group ----
  unsigned ea, eb = 0xFFFFFFFFu;
  {
    int g = lane;
    float4 mn = bounds[2*g], mx = bounds[2*g+1];
    float dx = fmaxf(fmaxf(mn.x - px, px - mx.x), 0.f);
    float dy = fmaxf(fmaxf(mn.y - py, py - mx.y), 0.f);
    float dz = fmaxf(fmaxf(mn.z - pz, pz - mx.z), 0.f);
    float lb = fmaf(dx,dx, fmaf(dy,dy, dz*dz)) * 0.999f - 1e-4f;
    ea = (fkey(lb) & 0xFFFFFF00u) | (unsigned)g;
  }
  if (lane + 64 < NGRP) {
    int g = lane + 64;
    float4 mn = bounds[2*g], mx = bounds[2*g+1];
    float dx = fmaxf(fmaxf(mn.x - px, px - mx.x), 0.f);
    float dy = fmaxf(fmaxf(mn.y - py, py - mx.y), 0.f);
    float dz = fmaxf(fmaxf(mn.z - pz, pz - mx.z), 0.f);
    float lb = fmaf(dx,dx, fmaf(dy,dy, dz*dz)) * 0.999f - 1e-4f;
    eb = (fkey(lb) & 0xFFFFFF00u) | (unsigned)g;
  }
  unsigned cur = ea < eb ? ea : eb;
  unsigned bak = ea < eb ? eb : ea;

  // ---- pop the 4 nearest groups (DPP min + scalar broadcast) ----
  int gs[4];
#pragma unroll
  for (int r = 0; r < 4; ++r) {
    unsigned m = wmin32d(cur);
    bool own = (cur == m);
    cur = own ? bak : cur;
    bak = own ? 0xFFFFFFFFu : bak;
    gs[r] = (int)(m & 0xFFu);
  }

  // ---- branchless: 4 atoms/lane -> exact u64 keys, sort-4 network ----
  float4 A[4]; int OI[4];
#pragma unroll
  for (int r = 0; r < 4; ++r) {
    int base = gs[r] << 6;
    A[r]  = atoms4s[base + lane];
    OI[r] = origid [base + lane];
  }
  ull E[4];
#pragma unroll
  for (int r = 0; r < 4; ++r) {
    float dotp = fmaf(px,A[r].x, fmaf(py,A[r].y, pz*A[r].z));
    float d2 = (x2 + A[r].w) - 2.f*dotp;     // reference expansion metric
    E[r] = ((ull)fkey(d2) << 32) | (unsigned)OI[r];
  }
  cswap(E[0],E[1]); cswap(E[2],E[3]); cswap(E[0],E[2]);
  cswap(E[1],E[3]); cswap(E[1],E[2]);

  // ---- 16-round DPP cursor merge over 64x4 candidates (exact) ----
  ull c64 = E[0], l1 = E[1], l2 = E[2], l3 = E[3];
  ull res = ~0ull, m64 = 0;
#pragma unroll
  for (int r = 0; r < KNN; ++r) {
    m64 = wmin64d(c64);                      // wave-uniform scalar
    if (lane == r) res = m64;
    bool own = (c64 == m64);
    c64 = own ? l1 : c64;
    l1  = own ? l2 : l1;
    l2  = own ? l3 : l2;
    l3  = own ? ~0ull : l3;
  }
  ull lv = res;                              // lanes 0..15: top-16 keys
  ull thresh = m64;                          // 16th best (wave-uniform)

  // ---- residual groups: pop while lb < thresh ----
  for (int it = 0; it < NGRP - 4; ++it) {
    unsigned m = wmin32d(cur);
    if ((m & 0xFFFFFF00u) >= (unsigned)(thresh >> 32)) break;   // prune done
    bool own = (cur == m);
    cur = own ? bak : cur;
    bak = own ? 0xFFFFFFFFu : bak;
    int base = (int)(m & 0xFFu) << 6;

    float4 a = atoms4s[base + lane];
    int oi = origid[base + lane];
    float dotp = fmaf(px,a.x, fmaf(py,a.y, pz*a.z));
    float d2 = (x2 + a.w) - 2.f*dotp;
    ull key = ((ull)fkey(d2) << 32) | (unsigned)oi;

    ull mk = __ballot(key < thresh);
    while (mk) {
      int src = (int)(__ffsll(mk) - 1);      // wave-uniform
      mk &= mk - 1;
      unsigned klo = (unsigned)__builtin_amdgcn_readlane((int)(unsigned)key, src);
      unsigned khi = (unsigned)__builtin_amdgcn_readlane((int)(unsigned)(key >> 32), src);
      ull kc = ((ull)khi << 32) | klo;
      if (kc < thresh) {
        bool ins = (lane < KNN) && (kc < lv);
        // shfl_up(…,1) == row_shr:1 (0x111). (0x101 = row_shl = WRONG, R7 bug)
        unsigned pvlo = (unsigned)__builtin_amdgcn_update_dpp(0, (int)(unsigned)lv,        0x111, 0xF, 0xF, false);
        unsigned pvhi = (unsigned)__builtin_amdgcn_update_dpp(0, (int)(unsigned)(lv>>32), 0x111, 0xF, 0xF, false);
        int pins      =           __builtin_amdgcn_update_dpp(0, ins ? 1 : 0,              0x111, 0xF, 0xF, false);
        if (ins) lv = pins ? (((ull)pvhi << 32) | pvlo) : kc;
        unsigned tlo = (unsigned)__builtin_amdgcn_readlane((int)(unsigned)lv, KNN-1);
        unsigned thi = (unsigned)__builtin_amdgcn_readlane((int)(unsigned)(lv >> 32), KNN-1);
        thresh = ((ull)thi << 32) | tlo;
      }
    }
  }

  if (lane < KNN) {
    int oi = (int)(unsigned)(lv & 0xFFFFFFFFull);
    float bx = atom_xyz[oi*3+0], by = atom_xyz[oi*3+1], bz = atom_xyz[oi*3+2];
    float dx = px - bx, dy = py - by, dz = pz - bz;
    float dd = fmaf(dx,dx, fmaf(dy,dy, dz*dz));    // exact recompute (reference)
    pairs[n*KNN + lane] = make_int2(oi, __float_as_int(1.f / dd));
  }
}

// ---------------------------------------------------------------------------
// a1 row from precomputed u': a1 = leaky(u'[idx] + iv * wiv)
// ---------------------------------------------------------------------------
__device__ __forceinline__ void a1_row(const float* __restrict__ tu, int idx,
                                       float iv, const float* wiv, float* a) {
  const float4* up = (const float4*)(tu + (size_t)idx*16);
  float4 r0 = up[0], r1 = up[1], r2 = up[2], r3 = up[3];
  float u[16];
  u[0]=r0.x; u[1]=r0.y; u[2]=r0.z; u[3]=r0.w;
  u[4]=r1.x; u[5]=r1.y; u[6]=r1.z; u[7]=r1.w;
  u[8]=r2.x; u[9]=r2.y; u[10]=r2.z; u[11]=r2.w;
  u[12]=r3.x; u[13]=r3.y; u[14]=r3.z; u[15]=r3.w;
#pragma unroll
  for (int j = 0; j < 16; ++j) a[j] = leaky(fmaf(iv, wiv[j], u[j]));
}

// ---------------------------------------------------------------------------
// K3: BN1 statistics (slim: gather u' + 16 fma) via LDS transpose reduction
// gstats layout: [sum1(16) | sq1(16) | sum2(16) | sq2(16)]
// ---------------------------------------------------------------------------
__global__ void __launch_bounds__(256, 6) k3_stats1(
    const int2* __restrict__ pairs, const float* __restrict__ tu,
    const float* __restrict__ W1, float* __restrict__ gstats) {
  __shared__ float wiv[16];
  __shared__ float buf[16*16*17];
  int tid = threadIdx.x;
  if (tid < 16) wiv[tid] = W1[256 + tid];
  __syncthreads();

  int g = blockIdx.x * 256 + tid;
  int p = tid >> 4, k = tid & 15;
  int2 pr = pairs[g];
  int idx = pr.x;
  float iv = __int_as_float(pr.y);
  float a[16];
  a1_row(tu, idx, iv, wiv, a);

  float* myrow = &buf[(p*16 + k)*17];
  int p2 = tid >> 4, j2 = tid & 15;
#pragma unroll
  for (int j = 0; j < 16; ++j) myrow[j] = a[j];
  __syncthreads();
  float s = 0.f;
#pragma unroll
  for (int kk = 0; kk < 16; ++kk) s += buf[(p2*16+kk)*17 + j2];
  __syncthreads();
#pragma unroll
  for (int j = 0; j < 16; ++j) myrow[j] = a[j]*a[j];
  __syncthreads();
  float q = 0.f;
#pragma unroll
  for (int kk = 0; kk < 16; ++kk) q += buf[(p2*16+kk)*17 + j2];
  __syncthreads();
  buf[p2*17 + j2] = s;
  buf[289 + p2*17 + j2] = q;
  __syncthreads();
  if (tid < 16) {
    float t1 = 0.f, t2 = 0.f;
#pragma unroll
    for (int pp = 0; pp < 16; ++pp) { t1 += buf[pp*17 + tid]; t2 += buf[289 + pp*17 + tid]; }
    atomicAdd(&gstats[tid],      t1);
    atomicAdd(&gstats[16 + tid], t2);
  }
}

// ---------------------------------------------------------------------------
// K4: a1 (slim), BN1 -> h, fx1 = sum_k h; a2 = leaky(h@W2+b2), s2 = sum_k a2;
// BN2 stats via LDS transpose machinery.
// ---------------------------------------------------------------------------
__global__ void __launch_bounds__(256, 4) k4_main(
    const int2* __restrict__ pairs, const float* __restrict__ tu,
    const float* __restrict__ W1,
    const float* __restrict__ W2, const float* __restrict__ b2,
    const float* __restrict__ g1, const float* __restrict__ be1,
    float* __restrict__ fx1_out, float* __restrict__ s2_out,
    float* __restrict__ gstats) {
  __shared__ float wiv[16], w2s[256], b2s[16];
  __shared__ float sc1[16], sh1[16];
  __shared__ float buf[16*16*17];
  int tid = threadIdx.x;
  w2s[tid] = W2[tid];
  if (tid < 16) { wiv[tid] = W1[256 + tid]; b2s[tid] = b2[tid]; }
  if (tid < 16) {
    float mean = gstats[tid]    * (1.f/BN_COUNT);
    float var  = gstats[16+tid] * (1.f/BN_COUNT) - mean*mean;
    float sC = g1[tid] / sqrtf(var + EPS);
    sc1[tid] = sC;
    sh1[tid] = be1[tid] - mean * sC;
  }
  __syncthreads();

  int g = blockIdx.x * 256 + tid;
  int p = tid >> 4, k = tid & 15;
  int2 pr = pairs[g];
  int idx = pr.x;
  float iv = __int_as_float(pr.y);
  float h[16], a2[16];
  a1_row(tu, idx, iv, wiv, h);               // h = a1
#pragma unroll
  for (int j = 0; j < 16; ++j) h[j] = fmaf(h[j], sc1[j], sh1[j]);
#pragma unroll
  for (int j = 0; j < 16; ++j) {
    float accj = b2s[j];
#pragma unroll
    for (int i = 0; i < 16; ++i) accj = fmaf(h[i], w2s[i*16+j], accj);
    a2[j] = leaky(accj);
  }

  float* myrow = &buf[(p*16 + k)*17];
  int p2 = tid >> 4, j2 = tid & 15;
#pragma unroll
  for (int j = 0; j < 16; ++j) myrow[j] = h[j];
  __syncthreads();
  {
    float s = 0.f;
#pragma unroll
    for (int kk = 0; kk < 16; ++kk) s += buf[(p2*16+kk)*17 + j2];
    fx1_out[(size_t)blockIdx.x*256 + tid] = s;
  }
  __syncthreads();
#pragma unroll
  for (int j = 0; j < 16; ++j) myrow[j] = a2[j];
  __syncthreads();
  float s2v = 0.f;
#pragma unroll
  for (int kk = 0; kk < 16; ++kk) s2v += buf[(p2*16+kk)*17 + j2];
  s2_out[(size_t)blockIdx.x*256 + tid] = s2v;
  __syncthreads();
#pragma unroll
  for (int j = 0; j < 16; ++j) myrow[j] = a2[j]*a2[j];
  __syncthreads();
  float q2v = 0.f;
#pragma unroll
  for (int kk = 0; kk < 16; ++kk) q2v += buf[(p2*16+kk)*17 + j2];
  __syncthreads();
  buf[p2*17 + j2] = s2v;
  buf[289 + p2*17 + j2] = q2v;
  __syncthreads();
  if (tid < 16) {
    float t1 = 0.f, t2 = 0.f;
#pragma unroll
    for (int pp = 0; pp < 16; ++pp) { t1 += buf[pp*17 + tid]; t2 += buf[289 + pp*17 + tid]; }
    atomicAdd(&gstats[32 + tid], t1);
    atomicAdd(&gstats[48 + tid], t2);
  }
}

// ---------------------------------------------------------------------------
// K5: fx2 = scale2*s2 + 16*shift2 ; out = [fx1, fx2] @ W3 + b3
// ---------------------------------------------------------------------------
__global__ void __launch_bounds__(256) k5_final(
    const float* __restrict__ fx1_in, const float* __restrict__ s2_in,
    const float* __restrict__ gstats,
    const float* __restrict__ W3, const float* __restrict__ b3,
    const float* __restrict__ g2, const float* __restrict__ be2,
    float* __restrict__ out) {
  __shared__ float w[512], bb[16], sc2[16], sh2[16];
  int tid = threadIdx.x;
  w[tid] = W3[tid]; w[256+tid] = W3[256+tid];
  if (tid < 16) {
    bb[tid] = b3[tid];
    float mean = gstats[32+tid] * (1.f/BN_COUNT);
    float var  = gstats[48+tid] * (1.f/BN_COUNT) - mean*mean;
    float s = g2[tid] / sqrtf(var + EPS);
    sc2[tid] = s;
    sh2[tid] = be2[tid] - mean * s;
  }
  __syncthreads();
  int n = blockIdx.x * 256 + tid;
  if (n >= N_PTS) return;

  const float4* f1p = (const float4*)(fx1_in + (size_t)n*16);
  const float4* f2p = (const float4*)(s2_in  + (size_t)n*16);
  float4 x0=f1p[0], x1=f1p[1], x2=f1p[2], x3=f1p[3];
  float4 y0=f2p[0], y1=f2p[1], y2=f2p[2], y3=f2p[3];
  float f1[16] = {x0.x,x0.y,x0.z,x0.w, x1.x,x1.y,x1.z,x1.w,
                  x2.x,x2.y,x2.z,x2.w, x3.x,x3.y,x3.z,x3.w};
  float f2[16] = {y0.x,y0.y,y0.z,y0.w, y1.x,y1.y,y1.z,y1.w,
                  y2.x,y2.y,y2.z,y2.w, y3.x,y3.y,y3.z,y3.w};
#pragma unroll
  for (int i = 0; i < 16; ++i) f2[i] = fmaf(sc2[i], f2[i], 16.f * sh2[i]);

  float4* op = (float4*)(out + (size_t)n*16);
  float o[16];
#pragma unroll
  for (int j = 0; j < 16; ++j) {
    float accj = bb[j];
#pragma unroll
    for (int i = 0; i < 16; ++i) accj = fmaf(f1[i], w[i*16+j], accj);
#pragma unroll
    for (int i = 0; i < 16; ++i) accj = fmaf(f2[i], w[(16+i)*16+j], accj);
    o[j] = accj;
  }
  op[0] = make_float4(o[0], o[1], o[2], o[3]);
  op[1] = make_float4(o[4], o[5], o[6], o[7]);
  op[2] = make_float4(o[8], o[9], o[10], o[11]);
  op[3] = make_float4(o[12], o[13], o[14], o[15]);
}

// ---------------------------------------------------------------------------
extern "C" void kernel_launch(void* const* d_in, const int* in_sizes, int n_in,
                              void* d_out, int out_size, void* d_ws, size_t ws_size,
                              hipStream_t stream) {
  const float* xyz        = (const float*)d_in[0];
  const float* atom_xyz   = (const float*)d_in[1];
  const float* atom_types = (const float*)d_in[2];
  const float* Wt1 = (const float*)d_in[3];  const float* bt1 = (const float*)d_in[4];
  const float* Wt2 = (const float*)d_in[5];  const float* bt2 = (const float*)d_in[6];
  const float* Wt3 = (const float*)d_in[7];  const float* bt3 = (const float*)d_in[8];
  const float* W1  = (const float*)d_in[9];  const float* b1  = (const float*)d_in[10];
  const float* W2  = (const float*)d_in[11]; const float* b2  = (const float*)d_in[12];
  const float* W3  = (const float*)d_in[13]; const float* b3  = (const float*)d_in[14];
  const float* g1  = (const float*)d_in[15]; const float* be1 = (const float*)d_in[16];
  const float* g2  = (const float*)d_in[17]; const float* be2 = (const float*)d_in[18];
  float* out = (float*)d_out;

  float* ws = (float*)d_ws;
  float4* atoms4   = (float4*)ws;                  // 8064*4    = 32256
  float*  tu       = ws + 32256;                   // 8000*16   = 128000  (u' = t@W1+b1)
  int2*   pairs    = (int2*)(ws + 160256);         // 480000*2  = 960000  (idx, invd)
  float*  fx1      = ws + 1120256;                 // 480000  (k4 output)
  float*  s2       = ws + 1600256;                 // 480000
  float*  gstats   = ws + 2080256;                 // 64
  // kNN accel structures live in fx1's span until k2 completes (stream-ordered):
  float4* atoms4s  = (float4*)(ws + 1120256);      // 32000
  int*    origid   = (int*)(ws + 1152256);         // 8000
  float4* bounds   = (float4*)(ws + 1160256);      // 1000

  k1_prep<<<32, 256, 0, stream>>>(atom_xyz, atom_types, Wt1, bt1, Wt2, bt2,
                                  Wt3, bt3, W1, b1, atoms4, tu, gstats);
  k_sort<<<1, 1024, 0, stream>>>(atoms4, atoms4s, origid);
  k_bounds<<<32, 256, 0, stream>>>(atoms4s, bounds);
  k2_knn<<<7500, 256, 0, stream>>>(xyz, atoms4s, origid, bounds, atom_xyz, pairs);
  k3_stats1<<<1875, 256, 0, stream>>>(pairs, tu, W1, gstats);
  k4_main<<<1875, 256, 0, stream>>>(pairs, tu, W1, W2, b2, g1, be1,
                                    fx1, s2, gstats);
  k5_final<<<118, 256, 0, stream>>>(fx1, s2, gstats, W3, b3, g2, be2, out);
}

// Round 9
// 235.732 us; speedup vs baseline: 2.2689x; 1.1143x over previous
//
#include <hip/hip_runtime.h>

#define N_PTS   30000
#define M_ATOMS 8000
#define D       16
#define KNN     16
#define NGRP    125           // 8000 / 64 exactly
#define EPS     1e-5f
#define SLOPE   0.2f
#define BN_COUNT 480000.0f    // N_PTS * KNN

typedef unsigned long long ull;

__device__ __forceinline__ float leaky(float x) { return x > 0.f ? x : SLOPE * x; }

// sortable key: strictly monotone bijection float -> u32 (and inverse)
__device__ __forceinline__ unsigned fkey(float f) {
  unsigned u = __float_as_uint(f);
  return u ^ ((u & 0x80000000u) ? 0xFFFFFFFFu : 0x80000000u);
}
__device__ __forceinline__ float unfkey(unsigned e) {
  unsigned u = (e & 0x80000000u) ? (e ^ 0x80000000u) : ~e;
  return __uint_as_float(u);
}

// ---- DPP wave-min reduction (row_shr:1/2/4/8 -> bcast15 -> bcast31 -> lane63)
#define DPPSTEP32(v, CTRL) {                                                   \
  unsigned t_ = (unsigned)__builtin_amdgcn_update_dpp(-1, (int)(v), CTRL, 0xF, 0xF, false); \
  (v) = t_ < (v) ? t_ : (v); }

__device__ __forceinline__ unsigned wmin32d(unsigned v) {
  DPPSTEP32(v, 0x111); DPPSTEP32(v, 0x112); DPPSTEP32(v, 0x114);
  DPPSTEP32(v, 0x118); DPPSTEP32(v, 0x142); DPPSTEP32(v, 0x143);
  return (unsigned)__builtin_amdgcn_readlane((int)v, 63);   // wave-uniform
}

__device__ __forceinline__ void cswap(ull& a, ull& b) {
  ull mn = a < b ? a : b, mx = a < b ? b : a;
  a = mn; b = mx;
}

__device__ __forceinline__ int morton_cell(float x, float y, float z) {
  int cx = min(max((int)floorf((x + 4.f) * 2.f), 0), 15);
  int cy = min(max((int)floorf((y + 4.f) * 2.f), 0), 15);
  int cz = min(max((int)floorf((z + 4.f) * 2.f), 0), 15);
  int c = 0;
#pragma unroll
  for (int b = 0; b < 4; ++b)
    c |= (((cx>>b)&1) << (3*b)) | (((cy>>b)&1) << (3*b+1)) | (((cz>>b)&1) << (3*b+2));
  return c;
}

// ---------------------------------------------------------------------------
// K_A: block 0 = zero gstats + Morton counting sort + group AABBs (LDS
// atomics on fkey-encoded coords). Blocks 1..32 = atom MLP -> u' = t@W1+b1.
// ---------------------------------------------------------------------------
#define LAYER(IN, OUT, W, B)                                        \
  _Pragma("unroll") for (int j = 0; j < 16; ++j) {                  \
    float acc = B[j];                                               \
    _Pragma("unroll") for (int i = 0; i < 16; ++i)                  \
      acc = fmaf(IN[i], W[i*16+j], acc);                            \
    OUT[j] = leaky(acc);                                            \
  }

__global__ void __launch_bounds__(256) kA_prep(
    const float* __restrict__ atom_xyz, const float* __restrict__ atom_types,
    const float* __restrict__ Wt1, const float* __restrict__ bt1,
    const float* __restrict__ Wt2, const float* __restrict__ bt2,
    const float* __restrict__ Wt3, const float* __restrict__ bt3,
    const float* __restrict__ W1, const float* __restrict__ b1,
    float* __restrict__ tu_out, float4* __restrict__ atoms4s,
    int* __restrict__ origid, float4* __restrict__ bounds,
    float* __restrict__ gstats) {
  int tid = threadIdx.x;
  if (blockIdx.x == 0) {
    __shared__ int h0[4096], h1[4096];
    __shared__ unsigned bmn[375], bmx[375];
    for (int i = tid; i < 4096; i += 256) { h0[i] = 0; }
    for (int i = tid; i < 375; i += 256) { bmn[i] = 0xFFFFFFFFu; bmx[i] = 0u; }
    for (int i = tid; i < 288; i += 256) gstats[i] = 0.f;   // BN1 8x32 + BN2 32
    __syncthreads();
    // histogram
    for (int r = 0; r < 32; ++r) {
      int m = r*256 + tid;
      if (m < M_ATOMS) {
        int c = morton_cell(atom_xyz[m*3], atom_xyz[m*3+1], atom_xyz[m*3+2]);
        atomicAdd(&h0[c], 1);
      }
    }
    __syncthreads();
    // inclusive scan (Hillis-Steele ping-pong, 12 steps)
    int* src = h0; int* dst = h1;
    for (int off = 1; off < 4096; off <<= 1) {
      for (int i = tid; i < 4096; i += 256) {
        int v = src[i];
        if (i >= off) v += src[i-off];
        dst[i] = v;
      }
      __syncthreads();
      int* t = src; src = dst; dst = t;
    }
    for (int i = tid; i < 4096; i += 256) dst[i] = i ? src[i-1] : 0;  // exclusive
    __syncthreads();
    // scatter + per-group bounds via LDS atomics
    for (int r = 0; r < 32; ++r) {
      int m = r*256 + tid;
      if (m < M_ATOMS) {
        float x = atom_xyz[m*3], y = atom_xyz[m*3+1], z = atom_xyz[m*3+2];
        int c = morton_cell(x, y, z);
        int pos = atomicAdd(&dst[c], 1);
        atoms4s[pos] = make_float4(x, y, z, fmaf(x,x, fmaf(y,y, z*z)));
        origid[pos] = m;
        int g = pos >> 6;
        atomicMin(&bmn[g],     fkey(x)); atomicMax(&bmx[g],     fkey(x));
        atomicMin(&bmn[125+g], fkey(y)); atomicMax(&bmx[125+g], fkey(y));
        atomicMin(&bmn[250+g], fkey(z)); atomicMax(&bmx[250+g], fkey(z));
      }
    }
    __syncthreads();
    if (tid < NGRP) {
      bounds[2*tid]   = make_float4(unfkey(bmn[tid]), unfkey(bmn[125+tid]),
                                    unfkey(bmn[250+tid]), 0.f);
      bounds[2*tid+1] = make_float4(unfkey(bmx[tid]), unfkey(bmx[125+tid]),
                                    unfkey(bmx[250+tid]), 0.f);
    }
  } else {
    __shared__ float w1[256], w2[256], w3[256], wc[256];
    __shared__ float bb1[16], bb2[16], bb3[16], bbc[16];
    w1[tid] = Wt1[tid]; w2[tid] = Wt2[tid]; w3[tid] = Wt3[tid]; wc[tid] = W1[tid];
    if (tid < 16) { bb1[tid] = bt1[tid]; bb2[tid] = bt2[tid];
                    bb3[tid] = bt3[tid]; bbc[tid] = b1[tid]; }
    __syncthreads();
    int m = (blockIdx.x - 1) * 256 + tid;
    if (m >= M_ATOMS) return;
    float u[16], v[16];
    const float4* tp = (const float4*)(atom_types + (size_t)m*16);
    float4 q0 = tp[0], q1 = tp[1], q2 = tp[2], q3 = tp[3];
    u[0]=q0.x; u[1]=q0.y; u[2]=q0.z; u[3]=q0.w;
    u[4]=q1.x; u[5]=q1.y; u[6]=q1.z; u[7]=q1.w;
    u[8]=q2.x; u[9]=q2.y; u[10]=q2.z; u[11]=q2.w;
    u[12]=q3.x; u[13]=q3.y; u[14]=q3.z; u[15]=q3.w;
    LAYER(u, v, w1, bb1);
    LAYER(v, u, w2, bb2);
    LAYER(u, v, w3, bb3);
    float up[16];
#pragma unroll
    for (int j = 0; j < 16; ++j) {
      float acc = bbc[j];
#pragma unroll
      for (int i = 0; i < 16; ++i) acc = fmaf(v[i], wc[i*16+j], acc);
      up[j] = acc;
    }
    float4* op = (float4*)(tu_out + (size_t)m*16);
    op[0] = make_float4(up[0], up[1], up[2], up[3]);
    op[1] = make_float4(up[4], up[5], up[6], up[7]);
    op[2] = make_float4(up[8], up[9], up[10], up[11]);
    op[3] = make_float4(up[12], up[13], up[14], up[15]);
  }
}

// ---------------------------------------------------------------------------
// K2 v7: exact 16-NN + fused BN1 stats.
// Merge pops on 32-bit fkey (wmin32d) + idx tie-break only when multiple
// owners (rare) — exact lexicographic (fkey, idx) pop order (per-lane lists
// sorted by full key => global min is at some lane's head).
// Epilogue: winners' a1 rows -> LDS transpose-reduce -> 8-way gstats copies.
// ---------------------------------------------------------------------------
__global__ void __launch_bounds__(256) k2_knn(
    const float* __restrict__ xyz, const float4* __restrict__ atoms4s,
    const int* __restrict__ origid, const float4* __restrict__ bounds,
    const float* __restrict__ atom_xyz, const float* __restrict__ tu,
    const float* __restrict__ W1,
    int2* __restrict__ pairs, float* __restrict__ gstats) {
  __shared__ float sbuf[4*16*20];            // [wave][row16][20] (16B-aligned rows)
  int tid = threadIdx.x;
  int lane = tid & 63;
  int wid = tid >> 6;
  int n = blockIdx.x * 4 + wid;              // 30000 = 7500*4 exactly

  float px = xyz[n*3+0], py = xyz[n*3+1], pz = xyz[n*3+2];
  float x2 = fmaf(px,px, fmaf(py,py, pz*pz));

  // ---- group lower-bound keys, packed u32: trunc24(fkey(lb)) | group ----
  unsigned ea, eb = 0xFFFFFFFFu;
  {
    int g = lane;
    float4 mn = bounds[2*g], mx = bounds[2*g+1];
    float dx = fmaxf(fmaxf(mn.x - px, px - mx.x), 0.f);
    float dy = fmaxf(fmaxf(mn.y - py, py - mx.y), 0.f);
    float dz = fmaxf(fmaxf(mn.z - pz, pz - mx.z), 0.f);
    float lb = fmaf(dx,dx, fmaf(dy,dy, dz*dz)) * 0.999f - 1e-4f;
    ea = (fkey(lb) & 0xFFFFFF00u) | (unsigned)g;
  }
  if (lane + 64 < NGRP) {
    int g = lane + 64;
    float4 mn = bounds[2*g], mx = bounds[2*g+1];
    float dx = fmaxf(fmaxf(mn.x - px, px - mx.x), 0.f);
    float dy = fmaxf(fmaxf(mn.y - py, py - mx.y), 0.f);
    float dz = fmaxf(fmaxf(mn.z - pz, pz - mx.z), 0.f);
    float lb = fmaf(dx,dx, fmaf(dy,dy, dz*dz)) * 0.999f - 1e-4f;
    eb = (fkey(lb) & 0xFFFFFF00u) | (unsigned)g;
  }
  unsigned cur = ea < eb ? ea : eb;
  unsigned bak = ea < eb ? eb : ea;

  // ---- pop the 4 nearest groups ----
  int gs[4];
#pragma unroll
  for (int r = 0; r < 4; ++r) {
    unsigned m = wmin32d(cur);
    bool own = (cur == m);
    cur = own ? bak : cur;
    bak = own ? 0xFFFFFFFFu : bak;
    gs[r] = (int)(m & 0xFFu);
  }

  // ---- 4 atoms/lane -> exact u64 keys, sort-4 by full key ----
  float4 A[4]; int OI[4];
#pragma unroll
  for (int r = 0; r < 4; ++r) {
    int base = gs[r] << 6;
    A[r]  = atoms4s[base + lane];
    OI[r] = origid [base + lane];
  }
  ull E[4];
#pragma unroll
  for (int r = 0; r < 4; ++r) {
    float dotp = fmaf(px,A[r].x, fmaf(py,A[r].y, pz*A[r].z));
    float d2 = (x2 + A[r].w) - 2.f*dotp;     // reference expansion metric
    E[r] = ((ull)fkey(d2) << 32) | (unsigned)OI[r];
  }
  cswap(E[0],E[1]); cswap(E[2],E[3]); cswap(E[0],E[2]);
  cswap(E[1],E[3]); cswap(E[1],E[2]);
  unsigned cf0 = (unsigned)(E[0] >> 32), ci0 = (unsigned)E[0];
  unsigned cf1 = (unsigned)(E[1] >> 32), ci1 = (unsigned)E[1];
  unsigned cf2 = (unsigned)(E[2] >> 32), ci2 = (unsigned)E[2];
  unsigned cf3 = (unsigned)(E[3] >> 32), ci3 = (unsigned)E[3];

  // ---- 16-round cursor merge: 32-bit fkey pop + rare idx tie-break ----
  ull res = ~0ull;
  unsigned mf = 0, mi = 0;
  for (int r = 0; r < KNN; ++r) {
    mf = wmin32d(cf0);
    ull ball = __ballot(cf0 == mf);
    if (__popcll(ball) == 1) {
      int srcl = (int)(__ffsll(ball) - 1);
      mi = (unsigned)__builtin_amdgcn_readlane((int)ci0, srcl);
    } else {
      unsigned cand = (cf0 == mf) ? ci0 : 0xFFFFFFFFu;
      mi = wmin32d(cand);
    }
    bool own = (cf0 == mf) && (ci0 == mi);   // unique: idx unique globally
    if (lane == r) res = (((ull)mf) << 32) | mi;
    cf0 = own ? cf1 : cf0; cf1 = own ? cf2 : cf1;
    cf2 = own ? cf3 : cf2; cf3 = own ? 0xFFFFFFFFu : cf3;
    ci0 = own ? ci1 : ci0; ci1 = own ? ci2 : ci1;
    ci2 = own ? ci3 : ci2; ci3 = own ? 0xFFFFFFFFu : ci3;
  }
  ull lv = res;                              // lanes 0..15: sorted top-16
  ull thresh = (((ull)mf) << 32) | mi;       // 16th best (wave-uniform)

  // ---- residual groups: pop while lb < thresh (proven R8 machinery) ----
  for (int it = 0; it < NGRP - 4; ++it) {
    unsigned m = wmin32d(cur);
    if ((m & 0xFFFFFF00u) >= (unsigned)(thresh >> 32)) break;
    bool own = (cur == m);
    cur = own ? bak : cur;
    bak = own ? 0xFFFFFFFFu : bak;
    int base = (int)(m & 0xFFu) << 6;

    float4 a = atoms4s[base + lane];
    int oi2 = origid[base + lane];
    float dotp = fmaf(px,a.x, fmaf(py,a.y, pz*a.z));
    float d2 = (x2 + a.w) - 2.f*dotp;
    ull key = ((ull)fkey(d2) << 32) | (unsigned)oi2;

    ull mk = __ballot(key < thresh);
    while (mk) {
      int src = (int)(__ffsll(mk) - 1);      // wave-uniform
      mk &= mk - 1;
      unsigned klo = (unsigned)__builtin_amdgcn_readlane((int)(unsigned)key, src);
      unsigned khi = (unsigned)__builtin_amdgcn_readlane((int)(unsigned)(key >> 32), src);
      ull kc = ((ull)khi << 32) | klo;
      if (kc < thresh) {
        bool ins = (lane < KNN) && (kc < lv);
        // shfl_up(…,1) == row_shr:1 (0x111)
        unsigned pvlo = (unsigned)__builtin_amdgcn_update_dpp(0, (int)(unsigned)lv,        0x111, 0xF, 0xF, false);
        unsigned pvhi = (unsigned)__builtin_amdgcn_update_dpp(0, (int)(unsigned)(lv>>32), 0x111, 0xF, 0xF, false);
        int pins      =           __builtin_amdgcn_update_dpp(0, ins ? 1 : 0,              0x111, 0xF, 0xF, false);
        if (ins) lv = pins ? (((ull)pvhi << 32) | pvlo) : kc;
        unsigned tlo = (unsigned)__builtin_amdgcn_readlane((int)(unsigned)lv, KNN-1);
        unsigned thi = (unsigned)__builtin_amdgcn_readlane((int)(unsigned)(lv >> 32), KNN-1);
        thresh = ((ull)thi << 32) | tlo;
      }
    }
  }

  // ---- epilogue: write pairs + fused BN1 stats ----
  int oi = (int)(unsigned)(lv & 0xFFFFFFFFull);
  float iv = 0.f;
  if (lane < KNN) {
    float bx = atom_xyz[oi*3+0], by = atom_xyz[oi*3+1], bz = atom_xyz[oi*3+2];
    float dx = px - bx, dy = py - by, dz = pz - bz;
    float dd = fmaf(dx,dx, fmaf(dy,dy, dz*dz));    // exact recompute (reference)
    iv = 1.f / dd;
    pairs[n*KNN + lane] = make_int2(oi, __float_as_int(iv));

    // a1 = leaky(u'[oi] + iv * W1[256..271])  -> LDS row
    const float4* up4 = (const float4*)(tu + (size_t)oi*16);
    float4 u0 = up4[0], u1 = up4[1], u2 = up4[2], u3 = up4[3];
    float4* row = (float4*)&sbuf[(wid*16 + lane)*20];
    float4 w;
    w.x = leaky(fmaf(iv, W1[256+ 0], u0.x)); w.y = leaky(fmaf(iv, W1[256+ 1], u0.y));
    w.z = leaky(fmaf(iv, W1[256+ 2], u0.z)); w.w = leaky(fmaf(iv, W1[256+ 3], u0.w));
    row[0] = w;
    w.x = leaky(fmaf(iv, W1[256+ 4], u1.x)); w.y = leaky(fmaf(iv, W1[256+ 5], u1.y));
    w.z = leaky(fmaf(iv, W1[256+ 6], u1.z)); w.w = leaky(fmaf(iv, W1[256+ 7], u1.w));
    row[1] = w;
    w.x = leaky(fmaf(iv, W1[256+ 8], u2.x)); w.y = leaky(fmaf(iv, W1[256+ 9], u2.y));
    w.z = leaky(fmaf(iv, W1[256+10], u2.z)); w.w = leaky(fmaf(iv, W1[256+11], u2.w));
    row[2] = w;
    w.x = leaky(fmaf(iv, W1[256+12], u3.x)); w.y = leaky(fmaf(iv, W1[256+13], u3.y));
    w.z = leaky(fmaf(iv, W1[256+14], u3.z)); w.w = leaky(fmaf(iv, W1[256+15], u3.w));
    row[3] = w;
  }
  __syncthreads();
  // transpose-reduce 64 rows x 16 ch: thread = (grp, ch), 4 rows each
  {
    int ch = tid & 15, grp = tid >> 4;
    float S = 0.f, Q = 0.f;
#pragma unroll
    for (int i = 0; i < 4; ++i) {
      float v = sbuf[(grp*4 + i)*20 + ch];
      S += v; Q += v*v;
    }
    __syncthreads();                          // all reads done before overwrite
    sbuf[grp*20 + ch] = S;
    sbuf[400 + grp*20 + ch] = Q;
  }
  __syncthreads();
  if (tid < 32) {
    int ch = tid & 15;
    int off = (tid < 16) ? 0 : 400;
    float s = 0.f;
#pragma unroll
    for (int g = 0; g < 16; ++g) s += sbuf[off + g*20 + ch];
    atomicAdd(&gstats[(blockIdx.x & 7)*32 + tid], s);
  }
}

// ---------------------------------------------------------------------------
// a1 row from precomputed u': a1 = leaky(u'[idx] + iv * wiv)
// ---------------------------------------------------------------------------
__device__ __forceinline__ void a1_row(const float* __restrict__ tu, int idx,
                                       float iv, const float* wiv, float* a) {
  const float4* up = (const float4*)(tu + (size_t)idx*16);
  float4 r0 = up[0], r1 = up[1], r2 = up[2], r3 = up[3];
  float u[16];
  u[0]=r0.x; u[1]=r0.y; u[2]=r0.z; u[3]=r0.w;
  u[4]=r1.x; u[5]=r1.y; u[6]=r1.z; u[7]=r1.w;
  u[8]=r2.x; u[9]=r2.y; u[10]=r2.z; u[11]=r2.w;
  u[12]=r3.x; u[13]=r3.y; u[14]=r3.z; u[15]=r3.w;
#pragma unroll
  for (int j = 0; j < 16; ++j) a[j] = leaky(fmaf(iv, wiv[j], u[j]));
}

// ---------------------------------------------------------------------------
// K4: a1, BN1 -> h, fx1 = sum_k h; a2 = leaky(h@W2+b2), s2 = sum_k a2;
// BN2 stats. BN1 stats come from gstats[0..255] (8 copies of 32).
// ---------------------------------------------------------------------------
__global__ void __launch_bounds__(256, 4) k4_main(
    const int2* __restrict__ pairs, const float* __restrict__ tu,
    const float* __restrict__ W1,
    const float* __restrict__ W2, const float* __restrict__ b2,
    const float* __restrict__ g1, const float* __restrict__ be1,
    float* __restrict__ fx1_out, float* __restrict__ s2_out,
    float* __restrict__ gstats) {
  __shared__ float wiv[16], w2s[256], b2s[16];
  __shared__ float sc1[16], sh1[16];
  __shared__ float buf[16*16*17];
  int tid = threadIdx.x;
  w2s[tid] = W2[tid];
  if (tid < 16) { wiv[tid] = W1[256 + tid]; b2s[tid] = b2[tid]; }
  if (tid < 16) {
    float s1 = 0.f, q1 = 0.f;
#pragma unroll
    for (int c = 0; c < 8; ++c) { s1 += gstats[c*32 + tid]; q1 += gstats[c*32 + 16 + tid]; }
    float mean = s1 * (1.f/BN_COUNT);
    float var  = q1 * (1.f/BN_COUNT) - mean*mean;
    float sC = g1[tid] / sqrtf(var + EPS);
    sc1[tid] = sC;
    sh1[tid] = be1[tid] - mean * sC;
  }
  __syncthreads();

  int g = blockIdx.x * 256 + tid;
  int p = tid >> 4, k = tid & 15;
  int2 pr = pairs[g];
  int idx = pr.x;
  float iv = __int_as_float(pr.y);
  float h[16], a2[16];
  a1_row(tu, idx, iv, wiv, h);               // h = a1
#pragma unroll
  for (int j = 0; j < 16; ++j) h[j] = fmaf(h[j], sc1[j], sh1[j]);
#pragma unroll
  for (int j = 0; j < 16; ++j) {
    float accj = b2s[j];
#pragma unroll
    for (int i = 0; i < 16; ++i) accj = fmaf(h[i], w2s[i*16+j], accj);
    a2[j] = leaky(accj);
  }

  float* myrow = &buf[(p*16 + k)*17];
  int p2 = tid >> 4, j2 = tid & 15;
#pragma unroll
  for (int j = 0; j < 16; ++j) myrow[j] = h[j];
  __syncthreads();
  {
    float s = 0.f;
#pragma unroll
    for (int kk = 0; kk < 16; ++kk) s += buf[(p2*16+kk)*17 + j2];
    fx1_out[(size_t)blockIdx.x*256 + tid] = s;
  }
  __syncthreads();
#pragma unroll
  for (int j = 0; j < 16; ++j) myrow[j] = a2[j];
  __syncthreads();
  float s2v = 0.f;
#pragma unroll
  for (int kk = 0; kk < 16; ++kk) s2v += buf[(p2*16+kk)*17 + j2];
  s2_out[(size_t)blockIdx.x*256 + tid] = s2v;
  __syncthreads();
#pragma unroll
  for (int j = 0; j < 16; ++j) myrow[j] = a2[j]*a2[j];
  __syncthreads();
  float q2v = 0.f;
#pragma unroll
  for (int kk = 0; kk < 16; ++kk) q2v += buf[(p2*16+kk)*17 + j2];
  __syncthreads();
  buf[p2*17 + j2] = s2v;
  buf[289 + p2*17 + j2] = q2v;
  __syncthreads();
  if (tid < 16) {
    float t1 = 0.f, t2 = 0.f;
#pragma unroll
    for (int pp = 0; pp < 16; ++pp) { t1 += buf[pp*17 + tid]; t2 += buf[289 + pp*17 + tid]; }
    atomicAdd(&gstats[256 + tid], t1);
    atomicAdd(&gstats[272 + tid], t2);
  }
}

// ---------------------------------------------------------------------------
// K5: fx2 = scale2*s2 + 16*shift2 ; out = [fx1, fx2] @ W3 + b3
// ---------------------------------------------------------------------------
__global__ void __launch_bounds__(256) k5_final(
    const float* __restrict__ fx1_in, const float* __restrict__ s2_in,
    const float* __restrict__ gstats,
    const float* __restrict__ W3, const float* __restrict__ b3,
    const float* __restrict__ g2, const float* __restrict__ be2,
    float* __restrict__ out) {
  __shared__ float w[512], bb[16], sc2[16], sh2[16];
  int tid = threadIdx.x;
  w[tid] = W3[tid]; w[256+tid] = W3[256+tid];
  if (tid < 16) {
    bb[tid] = b3[tid];
    float mean = gstats[256+tid] * (1.f/BN_COUNT);
    float var  = gstats[272+tid] * (1.f/BN_COUNT) - mean*mean;
    float s = g2[tid] / sqrtf(var + EPS);
    sc2[tid] = s;
    sh2[tid] = be2[tid] - mean * s;
  }
  __syncthreads();
  int n = blockIdx.x * 256 + tid;
  if (n >= N_PTS) return;

  const float4* f1p = (const float4*)(fx1_in + (size_t)n*16);
  const float4* f2p = (const float4*)(s2_in  + (size_t)n*16);
  float4 x0=f1p[0], x1=f1p[1], x2=f1p[2], x3=f1p[3];
  float4 y0=f2p[0], y1=f2p[1], y2=f2p[2], y3=f2p[3];
  float f1[16] = {x0.x,x0.y,x0.z,x0.w, x1.x,x1.y,x1.z,x1.w,
                  x2.x,x2.y,x2.z,x2.w, x3.x,x3.y,x3.z,x3.w};
  float f2[16] = {y0.x,y0.y,y0.z,y0.w, y1.x,y1.y,y1.z,y1.w,
                  y2.x,y2.y,y2.z,y2.w, y3.x,y3.y,y3.z,y3.w};
#pragma unroll
  for (int i = 0; i < 16; ++i) f2[i] = fmaf(sc2[i], f2[i], 16.f * sh2[i]);

  float4* op = (float4*)(out + (size_t)n*16);
  float o[16];
#pragma unroll
  for (int j = 0; j < 16; ++j) {
    float accj = bb[j];
#pragma unroll
    for (int i = 0; i < 16; ++i) accj = fmaf(f1[i], w[i*16+j], accj);
#pragma unroll
    for (int i = 0; i < 16; ++i) accj = fmaf(f2[i], w[(16+i)*16+j], accj);
    o[j] = accj;
  }
  op[0] = make_float4(o[0], o[1], o[2], o[3]);
  op[1] = make_float4(o[4], o[5], o[6], o[7]);
  op[2] = make_float4(o[8], o[9], o[10], o[11]);
  op[3] = make_float4(o[12], o[13], o[14], o[15]);
}

// ---------------------------------------------------------------------------
extern "C" void kernel_launch(void* const* d_in, const int* in_sizes, int n_in,
                              void* d_out, int out_size, void* d_ws, size_t ws_size,
                              hipStream_t stream) {
  const float* xyz        = (const float*)d_in[0];
  const float* atom_xyz   = (const float*)d_in[1];
  const float* atom_types = (const float*)d_in[2];
  const float* Wt1 = (const float*)d_in[3];  const float* bt1 = (const float*)d_in[4];
  const float* Wt2 = (const float*)d_in[5];  const float* bt2 = (const float*)d_in[6];
  const float* Wt3 = (const float*)d_in[7];  const float* bt3 = (const float*)d_in[8];
  const float* W1  = (const float*)d_in[9];  const float* b1  = (const float*)d_in[10];
  const float* W2  = (const float*)d_in[11]; const float* b2  = (const float*)d_in[12];
  const float* W3  = (const float*)d_in[13]; const float* b3  = (const float*)d_in[14];
  const float* g1  = (const float*)d_in[15]; const float* be1 = (const float*)d_in[16];
  const float* g2  = (const float*)d_in[17]; const float* be2 = (const float*)d_in[18];
  float* out = (float*)d_out;

  float* ws = (float*)d_ws;
  float*  tu       = ws;                           // 8000*16 = 128000
  int2*   pairs    = (int2*)(ws + 128000);         // 480000*2 = 960000
  float*  fx1      = ws + 1088000;                 // 480000 (k4 output)
  float*  s2       = ws + 1568000;                 // 480000
  float*  gstats   = ws + 2048000;                 // 288: [8x32 BN1 | 32 BN2]
  // kNN accel structures live in fx1's span until k2 completes (stream-ordered):
  float4* atoms4s  = (float4*)(ws + 1088000);      // 32000 floats
  int*    origid   = (int*)(ws + 1120000);         // 8000
  float4* bounds   = (float4*)(ws + 1128000);      // 1000 floats

  kA_prep<<<33, 256, 0, stream>>>(atom_xyz, atom_types, Wt1, bt1, Wt2, bt2,
                                  Wt3, bt3, W1, b1, tu, atoms4s, origid,
                                  bounds, gstats);
  k2_knn<<<7500, 256, 0, stream>>>(xyz, atoms4s, origid, bounds, atom_xyz,
                                   tu, W1, pairs, gstats);
  k4_main<<<1875, 256, 0, stream>>>(pairs, tu, W1, W2, b2, g1, be1,
                                    fx1, s2, gstats);
  k5_final<<<118, 256, 0, stream>>>(fx1, s2, gstats, W3, b3, g2, be2, out);
}

// Round 10
// 212.811 us; speedup vs baseline: 2.5133x; 1.1077x over previous
//
#include <hip/hip_runtime.h>

#define N_PTS   30000
#define M_ATOMS 8000
#define D       16
#define KNN     16
#define NGRP    125           // 8000 / 64 exactly
#define EPS     1e-5f
#define SLOPE   0.2f
#define BN_COUNT 480000.0f    // N_PTS * KNN

typedef unsigned long long ull;

__device__ __forceinline__ float leaky(float x) { return x > 0.f ? x : SLOPE * x; }

// sortable key: strictly monotone bijection float -> u32
__device__ __forceinline__ unsigned fkey(float f) {
  unsigned u = __float_as_uint(f);
  return u ^ ((u & 0x80000000u) ? 0xFFFFFFFFu : 0x80000000u);
}

// ---- DPP wave-min reduction (row_shr:1/2/4/8 -> bcast15 -> bcast31 -> lane63)
#define DPPSTEP32(v, CTRL) {                                                   \
  unsigned t_ = (unsigned)__builtin_amdgcn_update_dpp(-1, (int)(v), CTRL, 0xF, 0xF, false); \
  (v) = t_ < (v) ? t_ : (v); }

__device__ __forceinline__ unsigned wmin32d(unsigned v) {
  DPPSTEP32(v, 0x111); DPPSTEP32(v, 0x112); DPPSTEP32(v, 0x114);
  DPPSTEP32(v, 0x118); DPPSTEP32(v, 0x142); DPPSTEP32(v, 0x143);
  return (unsigned)__builtin_amdgcn_readlane((int)v, 63);   // wave-uniform
}

__device__ __forceinline__ void cswap(ull& a, ull& b) {
  ull mn = a < b ? a : b, mx = a < b ? b : a;
  a = mn; b = mx;
}

__device__ __forceinline__ int morton_cell(float x, float y, float z) {
  int cx = min(max((int)floorf((x + 4.f) * 2.f), 0), 15);
  int cy = min(max((int)floorf((y + 4.f) * 2.f), 0), 15);
  int cz = min(max((int)floorf((z + 4.f) * 2.f), 0), 15);
  int c = 0;
#pragma unroll
  for (int b = 0; b < 4; ++b)
    c |= (((cx>>b)&1) << (3*b)) | (((cy>>b)&1) << (3*b+1)) | (((cz>>b)&1) << (3*b+2));
  return c;
}

// ---------------------------------------------------------------------------
// KZ: zero 4096 histogram bins + 288 gstats
// ---------------------------------------------------------------------------
__global__ void __launch_bounds__(256) kZ_zero(int* __restrict__ bins,
                                               float* __restrict__ gstats) {
  int i = blockIdx.x * 256 + threadIdx.x;
  if (i < 4096) bins[i] = 0;
  else if (i - 4096 < 288) gstats[i - 4096] = 0.f;
}

// ---------------------------------------------------------------------------
// KA: atom MLP -> u' = t@W1+b1, plus global-atomic Morton histogram
// ---------------------------------------------------------------------------
#define LAYER(IN, OUT, W, B)                                        \
  _Pragma("unroll") for (int j = 0; j < 16; ++j) {                  \
    float acc = B[j];                                               \
    _Pragma("unroll") for (int i = 0; i < 16; ++i)                  \
      acc = fmaf(IN[i], W[i*16+j], acc);                            \
    OUT[j] = leaky(acc);                                            \
  }

__global__ void __launch_bounds__(256) kA_mlp_hist(
    const float* __restrict__ atom_xyz, const float* __restrict__ atom_types,
    const float* __restrict__ Wt1, const float* __restrict__ bt1,
    const float* __restrict__ Wt2, const float* __restrict__ bt2,
    const float* __restrict__ Wt3, const float* __restrict__ bt3,
    const float* __restrict__ W1, const float* __restrict__ b1,
    float* __restrict__ tu_out, int* __restrict__ bins) {
  __shared__ float w1[256], w2[256], w3[256], wc[256];
  __shared__ float bb1[16], bb2[16], bb3[16], bbc[16];
  int tid = threadIdx.x;
  w1[tid] = Wt1[tid]; w2[tid] = Wt2[tid]; w3[tid] = Wt3[tid]; wc[tid] = W1[tid];
  if (tid < 16) { bb1[tid] = bt1[tid]; bb2[tid] = bt2[tid];
                  bb3[tid] = bt3[tid]; bbc[tid] = b1[tid]; }
  __syncthreads();
  int m = blockIdx.x * 256 + tid;
  if (m >= M_ATOMS) return;

  // histogram (global atomics; 8000 adds over 4096 bins chip-wide)
  int c = morton_cell(atom_xyz[m*3], atom_xyz[m*3+1], atom_xyz[m*3+2]);
  atomicAdd(&bins[c], 1);

  float u[16], v[16];
  const float4* tp = (const float4*)(atom_types + (size_t)m*16);
  float4 q0 = tp[0], q1 = tp[1], q2 = tp[2], q3 = tp[3];
  u[0]=q0.x; u[1]=q0.y; u[2]=q0.z; u[3]=q0.w;
  u[4]=q1.x; u[5]=q1.y; u[6]=q1.z; u[7]=q1.w;
  u[8]=q2.x; u[9]=q2.y; u[10]=q2.z; u[11]=q2.w;
  u[12]=q3.x; u[13]=q3.y; u[14]=q3.z; u[15]=q3.w;
  LAYER(u, v, w1, bb1);
  LAYER(v, u, w2, bb2);
  LAYER(u, v, w3, bb3);
  float up[16];
#pragma unroll
  for (int j = 0; j < 16; ++j) {
    float acc = bbc[j];
#pragma unroll
    for (int i = 0; i < 16; ++i) acc = fmaf(v[i], wc[i*16+j], acc);
    up[j] = acc;
  }
  float4* op = (float4*)(tu_out + (size_t)m*16);
  op[0] = make_float4(up[0], up[1], up[2], up[3]);
  op[1] = make_float4(up[4], up[5], up[6], up[7]);
  op[2] = make_float4(up[8], up[9], up[10], up[11]);
  op[3] = make_float4(up[12], up[13], up[14], up[15]);
}

// ---------------------------------------------------------------------------
// KB: exclusive scan of 4096 bins -> cursors (1 block, 1024 threads; proven
// R8 ping-pong Hillis-Steele)
// ---------------------------------------------------------------------------
__global__ void __launch_bounds__(1024) kB_scan(
    const int* __restrict__ bins, int* __restrict__ cursors) {
  __shared__ int h0[4096], h1[4096];
  int tid = threadIdx.x;
  for (int i = tid; i < 4096; i += 1024) h0[i] = bins[i];
  __syncthreads();
  int* src = h0; int* dst = h1;
  for (int off = 1; off < 4096; off <<= 1) {
    for (int i = tid; i < 4096; i += 1024) {
      int v = src[i];
      if (i >= off) v += src[i-off];
      dst[i] = v;
    }
    __syncthreads();
    int* t = src; src = dst; dst = t;
  }
  for (int i = tid; i < 4096; i += 1024) cursors[i] = i ? src[i-1] : 0;
}

// ---------------------------------------------------------------------------
// KC: scatter atoms to Morton order via global cursor atomics
// ---------------------------------------------------------------------------
__global__ void __launch_bounds__(256) kC_scatter(
    const float* __restrict__ atom_xyz, int* __restrict__ cursors,
    float4* __restrict__ atoms4s, int* __restrict__ origid) {
  int m = blockIdx.x * 256 + threadIdx.x;
  if (m >= M_ATOMS) return;
  float x = atom_xyz[m*3], y = atom_xyz[m*3+1], z = atom_xyz[m*3+2];
  int c = morton_cell(x, y, z);
  int pos = atomicAdd(&cursors[c], 1);
  atoms4s[pos] = make_float4(x, y, z, fmaf(x,x, fmaf(y,y, z*z)));
  origid[pos] = m;
}

// ---------------------------------------------------------------------------
// K_BOUNDS: AABB per group of 64 sorted atoms. One wave per group (proven R8).
// ---------------------------------------------------------------------------
__global__ void __launch_bounds__(256) k_bounds(
    const float4* __restrict__ atoms4s, float4* __restrict__ bounds) {
  int lane = threadIdx.x & 63;
  int g = blockIdx.x * 4 + (threadIdx.x >> 6);
  if (g >= NGRP) return;
  float4 a = atoms4s[(g << 6) + lane];
  float mnx=a.x, mny=a.y, mnz=a.z, mxx=a.x, mxy=a.y, mxz=a.z;
#pragma unroll
  for (int off = 32; off; off >>= 1) {
    mnx = fminf(mnx, __shfl_xor(mnx, off, 64));
    mny = fminf(mny, __shfl_xor(mny, off, 64));
    mnz = fminf(mnz, __shfl_xor(mnz, off, 64));
    mxx = fmaxf(mxx, __shfl_xor(mxx, off, 64));
    mxy = fmaxf(mxy, __shfl_xor(mxy, off, 64));
    mxz = fmaxf(mxz, __shfl_xor(mxz, off, 64));
  }
  if (lane == 0) {
    bounds[2*g]   = make_float4(mnx, mny, mnz, 0.f);
    bounds[2*g+1] = make_float4(mxx, mxy, mxz, 0.f);
  }
}

// ---------------------------------------------------------------------------
// K2 v7 (unchanged from R9, proven): exact 16-NN + fused BN1 stats.
// ---------------------------------------------------------------------------
__global__ void __launch_bounds__(256) k2_knn(
    const float* __restrict__ xyz, const float4* __restrict__ atoms4s,
    const int* __restrict__ origid, const float4* __restrict__ bounds,
    const float* __restrict__ atom_xyz, const float* __restrict__ tu,
    const float* __restrict__ W1,
    int2* __restrict__ pairs, float* __restrict__ gstats) {
  __shared__ float sbuf[4*16*20];
  int tid = threadIdx.x;
  int lane = tid & 63;
  int wid = tid >> 6;
  int n = blockIdx.x * 4 + wid;              // 30000 = 7500*4 exactly

  float px = xyz[n*3+0], py = xyz[n*3+1], pz = xyz[n*3+2];
  float x2 = fmaf(px,px, fmaf(py,py, pz*pz));

  unsigned ea, eb = 0xFFFFFFFFu;
  {
    int g = lane;
    float4 mn = bounds[2*g], mx = bounds[2*g+1];
    float dx = fmaxf(fmaxf(mn.x - px, px - mx.x), 0.f);
    float dy = fmaxf(fmaxf(mn.y - py, py - mx.y), 0.f);
    float dz = fmaxf(fmaxf(mn.z - pz, pz - mx.z), 0.f);
    float lb = fmaf(dx,dx, fmaf(dy,dy, dz*dz)) * 0.999f - 1e-4f;
    ea = (fkey(lb) & 0xFFFFFF00u) | (unsigned)g;
  }
  if (lane + 64 < NGRP) {
    int g = lane + 64;
    float4 mn = bounds[2*g], mx = bounds[2*g+1];
    float dx = fmaxf(fmaxf(mn.x - px, px - mx.x), 0.f);
    float dy = fmaxf(fmaxf(mn.y - py, py - mx.y), 0.f);
    float dz = fmaxf(fmaxf(mn.z - pz, pz - mx.z), 0.f);
    float lb = fmaf(dx,dx, fmaf(dy,dy, dz*dz)) * 0.999f - 1e-4f;
    eb = (fkey(lb) & 0xFFFFFF00u) | (unsigned)g;
  }
  unsigned cur = ea < eb ? ea : eb;
  unsigned bak = ea < eb ? eb : ea;

  int gs[4];
#pragma unroll
  for (int r = 0; r < 4; ++r) {
    unsigned m = wmin32d(cur);
    bool own = (cur == m);
    cur = own ? bak : cur;
    bak = own ? 0xFFFFFFFFu : bak;
    gs[r] = (int)(m & 0xFFu);
  }

  float4 A[4]; int OI[4];
#pragma unroll
  for (int r = 0; r < 4; ++r) {
    int base = gs[r] << 6;
    A[r]  = atoms4s[base + lane];
    OI[r] = origid [base + lane];
  }
  ull E[4];
#pragma unroll
  for (int r = 0; r < 4; ++r) {
    float dotp = fmaf(px,A[r].x, fmaf(py,A[r].y, pz*A[r].z));
    float d2 = (x2 + A[r].w) - 2.f*dotp;     // reference expansion metric
    E[r] = ((ull)fkey(d2) << 32) | (unsigned)OI[r];
  }
  cswap(E[0],E[1]); cswap(E[2],E[3]); cswap(E[0],E[2]);
  cswap(E[1],E[3]); cswap(E[1],E[2]);
  unsigned cf0 = (unsigned)(E[0] >> 32), ci0 = (unsigned)E[0];
  unsigned cf1 = (unsigned)(E[1] >> 32), ci1 = (unsigned)E[1];
  unsigned cf2 = (unsigned)(E[2] >> 32), ci2 = (unsigned)E[2];
  unsigned cf3 = (unsigned)(E[3] >> 32), ci3 = (unsigned)E[3];

  ull res = ~0ull;
  unsigned mf = 0, mi = 0;
  for (int r = 0; r < KNN; ++r) {
    mf = wmin32d(cf0);
    ull ball = __ballot(cf0 == mf);
    if (__popcll(ball) == 1) {
      int srcl = (int)(__ffsll(ball) - 1);
      mi = (unsigned)__builtin_amdgcn_readlane((int)ci0, srcl);
    } else {
      unsigned cand = (cf0 == mf) ? ci0 : 0xFFFFFFFFu;
      mi = wmin32d(cand);
    }
    bool own = (cf0 == mf) && (ci0 == mi);
    if (lane == r) res = (((ull)mf) << 32) | mi;
    cf0 = own ? cf1 : cf0; cf1 = own ? cf2 : cf1;
    cf2 = own ? cf3 : cf2; cf3 = own ? 0xFFFFFFFFu : cf3;
    ci0 = own ? ci1 : ci0; ci1 = own ? ci2 : ci1;
    ci2 = own ? ci3 : ci2; ci3 = own ? 0xFFFFFFFFu : ci3;
  }
  ull lv = res;
  ull thresh = (((ull)mf) << 32) | mi;

  for (int it = 0; it < NGRP - 4; ++it) {
    unsigned m = wmin32d(cur);
    if ((m & 0xFFFFFF00u) >= (unsigned)(thresh >> 32)) break;
    bool own = (cur == m);
    cur = own ? bak : cur;
    bak = own ? 0xFFFFFFFFu : bak;
    int base = (int)(m & 0xFFu) << 6;

    float4 a = atoms4s[base + lane];
    int oi2 = origid[base + lane];
    float dotp = fmaf(px,a.x, fmaf(py,a.y, pz*a.z));
    float d2 = (x2 + a.w) - 2.f*dotp;
    ull key = ((ull)fkey(d2) << 32) | (unsigned)oi2;

    ull mk = __ballot(key < thresh);
    while (mk) {
      int src = (int)(__ffsll(mk) - 1);
      mk &= mk - 1;
      unsigned klo = (unsigned)__builtin_amdgcn_readlane((int)(unsigned)key, src);
      unsigned khi = (unsigned)__builtin_amdgcn_readlane((int)(unsigned)(key >> 32), src);
      ull kc = ((ull)khi << 32) | klo;
      if (kc < thresh) {
        bool ins = (lane < KNN) && (kc < lv);
        unsigned pvlo = (unsigned)__builtin_amdgcn_update_dpp(0, (int)(unsigned)lv,        0x111, 0xF, 0xF, false);
        unsigned pvhi = (unsigned)__builtin_amdgcn_update_dpp(0, (int)(unsigned)(lv>>32), 0x111, 0xF, 0xF, false);
        int pins      =           __builtin_amdgcn_update_dpp(0, ins ? 1 : 0,              0x111, 0xF, 0xF, false);
        if (ins) lv = pins ? (((ull)pvhi << 32) | pvlo) : kc;
        unsigned tlo = (unsigned)__builtin_amdgcn_readlane((int)(unsigned)lv, KNN-1);
        unsigned thi = (unsigned)__builtin_amdgcn_readlane((int)(unsigned)(lv >> 32), KNN-1);
        thresh = ((ull)thi << 32) | tlo;
      }
    }
  }

  int oi = (int)(unsigned)(lv & 0xFFFFFFFFull);
  float iv = 0.f;
  if (lane < KNN) {
    float bx = atom_xyz[oi*3+0], by = atom_xyz[oi*3+1], bz = atom_xyz[oi*3+2];
    float dx = px - bx, dy = py - by, dz = pz - bz;
    float dd = fmaf(dx,dx, fmaf(dy,dy, dz*dz));    // exact recompute (reference)
    iv = 1.f / dd;
    pairs[n*KNN + lane] = make_int2(oi, __float_as_int(iv));

    const float4* up4 = (const float4*)(tu + (size_t)oi*16);
    float4 u0 = up4[0], u1 = up4[1], u2 = up4[2], u3 = up4[3];
    float4* row = (float4*)&sbuf[(wid*16 + lane)*20];
    float4 w;
    w.x = leaky(fmaf(iv, W1[256+ 0], u0.x)); w.y = leaky(fmaf(iv, W1[256+ 1], u0.y));
    w.z = leaky(fmaf(iv, W1[256+ 2], u0.z)); w.w = leaky(fmaf(iv, W1[256+ 3], u0.w));
    row[0] = w;
    w.x = leaky(fmaf(iv, W1[256+ 4], u1.x)); w.y = leaky(fmaf(iv, W1[256+ 5], u1.y));
    w.z = leaky(fmaf(iv, W1[256+ 6], u1.z)); w.w = leaky(fmaf(iv, W1[256+ 7], u1.w));
    row[1] = w;
    w.x = leaky(fmaf(iv, W1[256+ 8], u2.x)); w.y = leaky(fmaf(iv, W1[256+ 9], u2.y));
    w.z = leaky(fmaf(iv, W1[256+10], u2.z)); w.w = leaky(fmaf(iv, W1[256+11], u2.w));
    row[2] = w;
    w.x = leaky(fmaf(iv, W1[256+12], u3.x)); w.y = leaky(fmaf(iv, W1[256+13], u3.y));
    w.z = leaky(fmaf(iv, W1[256+14], u3.z)); w.w = leaky(fmaf(iv, W1[256+15], u3.w));
    row[3] = w;
  }
  __syncthreads();
  {
    int ch = tid & 15, grp = tid >> 4;
    float S = 0.f, Q = 0.f;
#pragma unroll
    for (int i = 0; i < 4; ++i) {
      float v = sbuf[(grp*4 + i)*20 + ch];
      S += v; Q += v*v;
    }
    __syncthreads();
    sbuf[grp*20 + ch] = S;
    sbuf[400 + grp*20 + ch] = Q;
  }
  __syncthreads();
  if (tid < 32) {
    int ch = tid & 15;
    int off = (tid < 16) ? 0 : 400;
    float s = 0.f;
#pragma unroll
    for (int g = 0; g < 16; ++g) s += sbuf[off + g*20 + ch];
    atomicAdd(&gstats[(blockIdx.x & 7)*32 + tid], s);
  }
}

// ---------------------------------------------------------------------------
// a1 row from precomputed u': a1 = leaky(u'[idx] + iv * wiv)
// ---------------------------------------------------------------------------
__device__ __forceinline__ void a1_row(const float* __restrict__ tu, int idx,
                                       float iv, const float* wiv, float* a) {
  const float4* up = (const float4*)(tu + (size_t)idx*16);
  float4 r0 = up[0], r1 = up[1], r2 = up[2], r3 = up[3];
  float u[16];
  u[0]=r0.x; u[1]=r0.y; u[2]=r0.z; u[3]=r0.w;
  u[4]=r1.x; u[5]=r1.y; u[6]=r1.z; u[7]=r1.w;
  u[8]=r2.x; u[9]=r2.y; u[10]=r2.z; u[11]=r2.w;
  u[12]=r3.x; u[13]=r3.y; u[14]=r3.z; u[15]=r3.w;
#pragma unroll
  for (int j = 0; j < 16; ++j) a[j] = leaky(fmaf(iv, wiv[j], u[j]));
}

// ---------------------------------------------------------------------------
// K4 (unchanged from R9): a1, BN1 -> h, fx1; a2, s2; BN2 stats.
// ---------------------------------------------------------------------------
__global__ void __launch_bounds__(256, 4) k4_main(
    const int2* __restrict__ pairs, const float* __restrict__ tu,
    const float* __restrict__ W1,
    const float* __restrict__ W2, const float* __restrict__ b2,
    const float* __restrict__ g1, const float* __restrict__ be1,
    float* __restrict__ fx1_out, float* __restrict__ s2_out,
    float* __restrict__ gstats) {
  __shared__ float wiv[16], w2s[256], b2s[16];
  __shared__ float sc1[16], sh1[16];
  __shared__ float buf[16*16*17];
  int tid = threadIdx.x;
  w2s[tid] = W2[tid];
  if (tid < 16) { wiv[tid] = W1[256 + tid]; b2s[tid] = b2[tid]; }
  if (tid < 16) {
    float s1 = 0.f, q1 = 0.f;
#pragma unroll
    for (int c = 0; c < 8; ++c) { s1 += gstats[c*32 + tid]; q1 += gstats[c*32 + 16 + tid]; }
    float mean = s1 * (1.f/BN_COUNT);
    float var  = q1 * (1.f/BN_COUNT) - mean*mean;
    float sC = g1[tid] / sqrtf(var + EPS);
    sc1[tid] = sC;
    sh1[tid] = be1[tid] - mean * sC;
  }
  __syncthreads();

  int g = blockIdx.x * 256 + tid;
  int p = tid >> 4, k = tid & 15;
  int2 pr = pairs[g];
  int idx = pr.x;
  float iv = __int_as_float(pr.y);
  float h[16], a2[16];
  a1_row(tu, idx, iv, wiv, h);
#pragma unroll
  for (int j = 0; j < 16; ++j) h[j] = fmaf(h[j], sc1[j], sh1[j]);
#pragma unroll
  for (int j = 0; j < 16; ++j) {
    float accj = b2s[j];
#pragma unroll
    for (int i = 0; i < 16; ++i) accj = fmaf(h[i], w2s[i*16+j], accj);
    a2[j] = leaky(accj);
  }

  float* myrow = &buf[(p*16 + k)*17];
  int p2 = tid >> 4, j2 = tid & 15;
#pragma unroll
  for (int j = 0; j < 16; ++j) myrow[j] = h[j];
  __syncthreads();
  {
    float s = 0.f;
#pragma unroll
    for (int kk = 0; kk < 16; ++kk) s += buf[(p2*16+kk)*17 + j2];
    fx1_out[(size_t)blockIdx.x*256 + tid] = s;
  }
  __syncthreads();
#pragma unroll
  for (int j = 0; j < 16; ++j) myrow[j] = a2[j];
  __syncthreads();
  float s2v = 0.f;
#pragma unroll
  for (int kk = 0; kk < 16; ++kk) s2v += buf[(p2*16+kk)*17 + j2];
  s2_out[(size_t)blockIdx.x*256 + tid] = s2v;
  __syncthreads();
#pragma unroll
  for (int j = 0; j < 16; ++j) myrow[j] = a2[j]*a2[j];
  __syncthreads();
  float q2v = 0.f;
#pragma unroll
  for (int kk = 0; kk < 16; ++kk) q2v += buf[(p2*16+kk)*17 + j2];
  __syncthreads();
  buf[p2*17 + j2] = s2v;
  buf[289 + p2*17 + j2] = q2v;
  __syncthreads();
  if (tid < 16) {
    float t1 = 0.f, t2 = 0.f;
#pragma unroll
    for (int pp = 0; pp < 16; ++pp) { t1 += buf[pp*17 + tid]; t2 += buf[289 + pp*17 + tid]; }
    atomicAdd(&gstats[256 + tid], t1);
    atomicAdd(&gstats[272 + tid], t2);
  }
}

// ---------------------------------------------------------------------------
// K5 (unchanged): fx2 = scale2*s2 + 16*shift2 ; out = [fx1, fx2] @ W3 + b3
// ---------------------------------------------------------------------------
__global__ void __launch_bounds__(256) k5_final(
    const float* __restrict__ fx1_in, const float* __restrict__ s2_in,
    const float* __restrict__ gstats,
    const float* __restrict__ W3, const float* __restrict__ b3,
    const float* __restrict__ g2, const float* __restrict__ be2,
    float* __restrict__ out) {
  __shared__ float w[512], bb[16], sc2[16], sh2[16];
  int tid = threadIdx.x;
  w[tid] = W3[tid]; w[256+tid] = W3[256+tid];
  if (tid < 16) {
    bb[tid] = b3[tid];
    float mean = gstats[256+tid] * (1.f/BN_COUNT);
    float var  = gstats[272+tid] * (1.f/BN_COUNT) - mean*mean;
    float s = g2[tid] / sqrtf(var + EPS);
    sc2[tid] = s;
    sh2[tid] = be2[tid] - mean * s;
  }
  __syncthreads();
  int n = blockIdx.x * 256 + tid;
  if (n >= N_PTS) return;

  const float4* f1p = (const float4*)(fx1_in + (size_t)n*16);
  const float4* f2p = (const float4*)(s2_in  + (size_t)n*16);
  float4 x0=f1p[0], x1=f1p[1], x2=f1p[2], x3=f1p[3];
  float4 y0=f2p[0], y1=f2p[1], y2=f2p[2], y3=f2p[3];
  float f1[16] = {x0.x,x0.y,x0.z,x0.w, x1.x,x1.y,x1.z,x1.w,
                  x2.x,x2.y,x2.z,x2.w, x3.x,x3.y,x3.z,x3.w};
  float f2[16] = {y0.x,y0.y,y0.z,y0.w, y1.x,y1.y,y1.z,y1.w,
                  y2.x,y2.y,y2.z,y2.w, y3.x,y3.y,y3.z,y3.w};
#pragma unroll
  for (int i = 0; i < 16; ++i) f2[i] = fmaf(sc2[i], f2[i], 16.f * sh2[i]);

  float4* op = (float4*)(out + (size_t)n*16);
  float o[16];
#pragma unroll
  for (int j = 0; j < 16; ++j) {
    float accj = bb[j];
#pragma unroll
    for (int i = 0; i < 16; ++i) accj = fmaf(f1[i], w[i*16+j], accj);
#pragma unroll
    for (int i = 0; i < 16; ++i) accj = fmaf(f2[i], w[(16+i)*16+j], accj);
    o[j] = accj;
  }
  op[0] = make_float4(o[0], o[1], o[2], o[3]);
  op[1] = make_float4(o[4], o[5], o[6], o[7]);
  op[2] = make_float4(o[8], o[9], o[10], o[11]);
  op[3] = make_float4(o[12], o[13], o[14], o[15]);
}

// ---------------------------------------------------------------------------
extern "C" void kernel_launch(void* const* d_in, const int* in_sizes, int n_in,
                              void* d_out, int out_size, void* d_ws, size_t ws_size,
                              hipStream_t stream) {
  const float* xyz        = (const float*)d_in[0];
  const float* atom_xyz   = (const float*)d_in[1];
  const float* atom_types = (const float*)d_in[2];
  const float* Wt1 = (const float*)d_in[3];  const float* bt1 = (const float*)d_in[4];
  const float* Wt2 = (const float*)d_in[5];  const float* bt2 = (const float*)d_in[6];
  const float* Wt3 = (const float*)d_in[7];  const float* bt3 = (const float*)d_in[8];
  const float* W1  = (const float*)d_in[9];  const float* b1  = (const float*)d_in[10];
  const float* W2  = (const float*)d_in[11]; const float* b2  = (const float*)d_in[12];
  const float* W3  = (const float*)d_in[13]; const float* b3  = (const float*)d_in[14];
  const float* g1  = (const float*)d_in[15]; const float* be1 = (const float*)d_in[16];
  const float* g2  = (const float*)d_in[17]; const float* be2 = (const float*)d_in[18];
  float* out = (float*)d_out;

  float* ws = (float*)d_ws;
  float*  tu       = ws;                           // 8000*16 = 128000
  int2*   pairs    = (int2*)(ws + 128000);         // 480000*2 = 960000
  float*  fx1      = ws + 1088000;                 // 480000 (k4 output)
  float*  s2       = ws + 1568000;                 // 480000
  float*  gstats   = ws + 2048000;                 // 288: [8x32 BN1 | 32 BN2]
  int*    bins     = (int*)(ws + 2048288);         // 4096
  int*    cursors  = (int*)(ws + 2052384);         // 4096
  // kNN accel structures live in fx1's span until k2 completes (stream-ordered):
  float4* atoms4s  = (float4*)(ws + 1088000);      // 32000 floats
  int*    origid   = (int*)(ws + 1120000);         // 8000
  float4* bounds   = (float4*)(ws + 1128000);      // 1000 floats

  kZ_zero<<<18, 256, 0, stream>>>(bins, gstats);
  kA_mlp_hist<<<32, 256, 0, stream>>>(atom_xyz, atom_types, Wt1, bt1, Wt2, bt2,
                                      Wt3, bt3, W1, b1, tu, bins);
  kB_scan<<<1, 1024, 0, stream>>>(bins, cursors);
  kC_scatter<<<32, 256, 0, stream>>>(atom_xyz, cursors, atoms4s, origid);
  k_bounds<<<32, 256, 0, stream>>>(atoms4s, bounds);
  k2_knn<<<7500, 256, 0, stream>>>(xyz, atoms4s, origid, bounds, atom_xyz,
                                   tu, W1, pairs, gstats);
  k4_main<<<1875, 256, 0, stream>>>(pairs, tu, W1, W2, b2, g1, be1,
                                    fx1, s2, gstats);
  k5_final<<<118, 256, 0, stream>>>(fx1, s2, gstats, W3, b3, g2, be2, out);
}